// Round 2
// baseline (1124.434 us; speedup 1.0000x reference)
//
#include <hip/hip_runtime.h>

#define NN 100000
#define NE 220000
#define HD 128
#define NG 4096
#define NPE 5

// x[n][f] = embed[tok[n]][f] + bt[f] + sum_k pe[n][k]*Wt[k][f]
__global__ void k_compute_x(const int* __restrict__ tok,
                            const float* __restrict__ pe,
                            const float* __restrict__ embed,
                            const float* __restrict__ Wt,
                            const float* __restrict__ bt,
                            float* __restrict__ x) {
    int idx = blockIdx.x * blockDim.x + threadIdx.x;
    if (idx >= NN * HD) return;
    int n = idx >> 7, f = idx & 127;
    float acc = embed[tok[n] * HD + f] + bt[f];
    const float* pen = pe + n * NPE;
#pragma unroll
    for (int k = 0; k < NPE; ++k) acc += pen[k] * Wt[k * HD + f];
    x[idx] = acc;
}

__global__ void k_deg(const int* __restrict__ dst, float* __restrict__ deg) {
    int e = blockIdx.x * blockDim.x + threadIdx.x;
    if (e < NE) atomicAdd(&deg[dst[e]], 1.0f);
}

__global__ void k_dinv(float* __restrict__ deg) {
    int n = blockIdx.x * blockDim.x + threadIdx.x;
    if (n < NN) deg[n] = rsqrtf(deg[n] + 1.0f);
}

// aggX = x * dinv^2 (self-loop term), float4 per thread
__global__ void k_selfinit(const float* __restrict__ x, const float* __restrict__ dinv,
                           float* __restrict__ aggX) {
    int idx = blockIdx.x * blockDim.x + threadIdx.x;   // one float4
    if (idx >= NN * 32) return;
    int n = idx >> 5;
    float d = dinv[n];
    d = d * d;
    float4 v = ((const float4*)x)[idx];
    v.x *= d; v.y *= d; v.z *= d; v.w *= d;
    ((float4*)aggX)[idx] = v;
}

// aggX[dst] += x[src] * dinv[src]*dinv[dst]; one thread per (edge, float4)
__global__ void k_edge_agg(const float* __restrict__ x, const float* __restrict__ dinv,
                           const int* __restrict__ src, const int* __restrict__ dst,
                           float* __restrict__ aggX) {
    long long tid = (long long)blockIdx.x * blockDim.x + threadIdx.x;
    int e = (int)(tid >> 5);
    int q = (int)(tid & 31);
    if (e >= NE) return;
    int s = src[e], d = dst[e];
    float c = dinv[s] * dinv[d];
    float4 v = ((const float4*)(x + (size_t)s * HD))[q];
    float* out = aggX + (size_t)d * HD + q * 4;
    atomicAdd(out + 0, v.x * c);
    atomicAdd(out + 1, v.y * c);
    atomicAdd(out + 2, v.z * c);
    atomicAdd(out + 3, v.w * c);
}

// Fused: z[n] = relu(aggX[n]@W1 + b1) @ W2 ; agg2[n] = z[n]*dinv[n]^2
// Block: 256 threads, 32 nodes. LDS: W1 64KB + x-tile(transposed) 16KB.
// Thread (fq=tid&31, ng=tid>>5): 4 nodes (ng*4..+3) x 4 features (fq*4..+3).
// NN = 100000 = 3125*32 exactly -> no bounds checks.
__global__ __launch_bounds__(256, 1) void k_gcn_fused(
    const float* __restrict__ aggX, const float* __restrict__ W1,
    const float* __restrict__ b1, const float* __restrict__ W2,
    const float* __restrict__ dinv,
    float* __restrict__ z, float* __restrict__ agg2) {
    __shared__ float Wl[HD * HD];     // Wl[k*128+f]
    __shared__ float xs[HD][32];      // xs[k][node]
    int tid = threadIdx.x;
    int n0 = blockIdx.x * 32;

    // stage W1 (coalesced float4)
    {
        const float4* ws = (const float4*)W1;
        float4* wd = (float4*)Wl;
        for (int i = tid; i < HD * HD / 4; i += 256) wd[i] = ws[i];
    }
    // stage x-tile transposed: lane n = tid&31 reads row n0+n, quad kq
    {
        int n = tid & 31;
        int kq0 = tid >> 5;
        const float4* xsrc = (const float4*)(aggX + (size_t)(n0 + n) * HD);
#pragma unroll
        for (int j = 0; j < 4; ++j) {
            int kq = kq0 + j * 8;
            float4 v = xsrc[kq];
            xs[kq * 4 + 0][n] = v.x;
            xs[kq * 4 + 1][n] = v.y;
            xs[kq * 4 + 2][n] = v.z;
            xs[kq * 4 + 3][n] = v.w;
        }
    }
    __syncthreads();

    int fq = tid & 31;
    int ng = tid >> 5;
    float acc[4][4] = {{0.f}};
#pragma unroll 8
    for (int k = 0; k < HD; ++k) {
        float4 xv = *(const float4*)&xs[k][ng * 4];
        float4 wv = *(const float4*)&Wl[k * HD + fq * 4];
        acc[0][0] += xv.x * wv.x; acc[0][1] += xv.x * wv.y;
        acc[0][2] += xv.x * wv.z; acc[0][3] += xv.x * wv.w;
        acc[1][0] += xv.y * wv.x; acc[1][1] += xv.y * wv.y;
        acc[1][2] += xv.y * wv.z; acc[1][3] += xv.y * wv.w;
        acc[2][0] += xv.z * wv.x; acc[2][1] += xv.z * wv.y;
        acc[2][2] += xv.z * wv.z; acc[2][3] += xv.z * wv.w;
        acc[3][0] += xv.w * wv.x; acc[3][1] += xv.w * wv.y;
        acc[3][2] += xv.w * wv.z; acc[3][3] += xv.w * wv.w;
    }

    // epilogue: relu(acc + b1) dot W2, reduce over the 32 fq threads
    int f0 = fq * 4;
    float4 bb = *(const float4*)&b1[f0];
    float4 w2 = *(const float4*)&W2[f0];
    float part[4];
#pragma unroll
    for (int i = 0; i < 4; ++i) {
        part[i] = fmaxf(acc[i][0] + bb.x, 0.f) * w2.x
                + fmaxf(acc[i][1] + bb.y, 0.f) * w2.y
                + fmaxf(acc[i][2] + bb.z, 0.f) * w2.z
                + fmaxf(acc[i][3] + bb.w, 0.f) * w2.w;
    }
#pragma unroll
    for (int o = 16; o > 0; o >>= 1) {
#pragma unroll
        for (int i = 0; i < 4; ++i) part[i] += __shfl_down(part[i], o, 32);
    }
    if (fq == 0) {
#pragma unroll
        for (int i = 0; i < 4; ++i) {
            int n = n0 + ng * 4 + i;
            float dv = dinv[n];
            z[n] = part[i];
            agg2[n] = part[i] * dv * dv;
        }
    }
}

// agg2[dst] += z[src]*dinv[src]*dinv[dst]
__global__ void k_edge2(const float* __restrict__ z, const float* __restrict__ dinv,
                        const int* __restrict__ src, const int* __restrict__ dst,
                        float* __restrict__ agg2) {
    int e = blockIdx.x * blockDim.x + threadIdx.x;
    if (e >= NE) return;
    int s = src[e], d = dst[e];
    atomicAdd(&agg2[d], z[s] * dinv[s] * dinv[d]);
}

// y[batch[n]] += agg2[n] + b2
__global__ void k_final(const float* __restrict__ agg2, const float* __restrict__ b2,
                        const int* __restrict__ batch, float* __restrict__ y) {
    int n = blockIdx.x * blockDim.x + threadIdx.x;
    if (n >= NN) return;
    atomicAdd(&y[batch[n]], agg2[n] + b2[0]);
}

extern "C" void kernel_launch(void* const* d_in, const int* in_sizes, int n_in,
                              void* d_out, int out_size, void* d_ws, size_t ws_size,
                              hipStream_t stream) {
    const int*   tok   = (const int*)d_in[0];
    const float* pe    = (const float*)d_in[1];
    const int*   ei    = (const int*)d_in[2];
    const int*   vei   = (const int*)d_in[3];
    const int*   batch = (const int*)d_in[4];
    const float* embed = (const float*)d_in[5];
    const float* Wt    = (const float*)d_in[6];
    const float* bt    = (const float*)d_in[7];
    const float* W1    = (const float*)d_in[8];
    const float* b1    = (const float*)d_in[9];
    const float* W2    = (const float*)d_in[10];
    const float* b2    = (const float*)d_in[11];
    const float* Wv1   = (const float*)d_in[12];
    const float* bv1   = (const float*)d_in[13];
    const float* Wv2   = (const float*)d_in[14];
    const float* bv2   = (const float*)d_in[15];

    float* y = (float*)d_out;       // [NG]
    float* x = y + NG;              // [NN*HD], output 1

    float* aggX = (float*)d_ws;                 // [NN*HD]
    float* dinv = aggX + (size_t)NN * HD;       // [NN]
    float* z    = dinv + NN;                    // [NN]
    float* agg2 = z + NN;                       // [NN]

    hipMemsetAsync(y, 0, NG * sizeof(float), stream);
    k_compute_x<<<(NN * HD + 255) / 256, 256, 0, stream>>>(tok, pe, embed, Wt, bt, x);

    for (int br = 0; br < 2; ++br) {
        const int* src = br ? vei : ei;
        const int* dst = src + NE;
        const float* Wa = br ? Wv1 : W1;
        const float* ba = br ? bv1 : b1;
        const float* Wb = br ? Wv2 : W2;
        const float* bb = br ? bv2 : b2;

        hipMemsetAsync(dinv, 0, NN * sizeof(float), stream);
        k_deg<<<(NE + 255) / 256, 256, 0, stream>>>(dst, dinv);
        k_dinv<<<(NN + 255) / 256, 256, 0, stream>>>(dinv);
        k_selfinit<<<(NN * 32 + 255) / 256, 256, 0, stream>>>(x, dinv, aggX);
        k_edge_agg<<<(int)(((long long)NE * 32 + 255) / 256), 256, 0, stream>>>(x, dinv, src, dst, aggX);
        k_gcn_fused<<<NN / 32, 256, 0, stream>>>(aggX, Wa, ba, Wb, dinv, z, agg2);
        k_edge2<<<(NE + 255) / 256, 256, 0, stream>>>(z, dinv, src, dst, agg2);
        k_final<<<(NN + 255) / 256, 256, 0, stream>>>(agg2, bb, batch, y);
    }
}

// Round 3
// 497.892 us; speedup vs baseline: 2.2584x; 2.2584x over previous
//
#include <hip/hip_runtime.h>

#define NN 100000
#define NE 220000
#define HD 128
#define NG 4096
#define NPE 5
#define NB_SCAN ((NN + 255) / 256)   // 391

// x[n][f] = embed[tok[n]][f] + bt[f] + sum_k pe[n][k]*Wt[k][f]
__global__ void k_compute_x(const int* __restrict__ tok,
                            const float* __restrict__ pe,
                            const float* __restrict__ embed,
                            const float* __restrict__ Wt,
                            const float* __restrict__ bt,
                            float* __restrict__ x) {
    int idx = blockIdx.x * blockDim.x + threadIdx.x;
    if (idx >= NN * HD) return;
    int n = idx >> 7, f = idx & 127;
    float acc = embed[tok[n] * HD + f] + bt[f];
    const float* pen = pe + n * NPE;
#pragma unroll
    for (int k = 0; k < NPE; ++k) acc += pen[k] * Wt[k * HD + f];
    x[idx] = acc;
}

__global__ void k_deg(const int* __restrict__ dst, int* __restrict__ cnt) {
    int e = blockIdx.x * blockDim.x + threadIdx.x;
    if (e < NE) atomicAdd(&cnt[dst[e]], 1);
}

__global__ void k_dinv(const int* __restrict__ cnt, float* __restrict__ dinv) {
    int n = blockIdx.x * blockDim.x + threadIdx.x;
    if (n < NN) dinv[n] = rsqrtf((float)cnt[n] + 1.0f);
}

// Exclusive scan, two-level. Level 1: per-block 256-element scan.
__global__ void k_scan1(const int* __restrict__ cnt, int* __restrict__ off,
                        int* __restrict__ bsum) {
    __shared__ int s[256];
    int tid = threadIdx.x;
    int i = blockIdx.x * 256 + tid;
    int v = (i < NN) ? cnt[i] : 0;
    s[tid] = v;
    __syncthreads();
    for (int d = 1; d < 256; d <<= 1) {
        int t = (tid >= d) ? s[tid - d] : 0;
        __syncthreads();
        s[tid] += t;
        __syncthreads();
    }
    if (i < NN) off[i] = s[tid] - v;          // exclusive
    if (tid == 255) bsum[blockIdx.x] = s[255]; // block total
}

// Level 2: scan the 391 block sums (single block, 512 threads), in place.
__global__ void k_scan2(int* __restrict__ bsum) {
    __shared__ int s[512];
    int tid = threadIdx.x;
    int v = (tid < NB_SCAN) ? bsum[tid] : 0;
    s[tid] = v;
    __syncthreads();
    for (int d = 1; d < 512; d <<= 1) {
        int t = (tid >= d) ? s[tid - d] : 0;
        __syncthreads();
        s[tid] += t;
        __syncthreads();
    }
    if (tid < NB_SCAN) bsum[tid] = s[tid] - v; // exclusive
}

// Level 3: add block offset; also init cur = off.
__global__ void k_scan3(int* __restrict__ off, const int* __restrict__ bsum,
                        int* __restrict__ cur) {
    int i = blockIdx.x * 256 + threadIdx.x;
    if (i < NN) {
        int o = off[i] + bsum[blockIdx.x];
        off[i] = o;
        cur[i] = o;
    }
}

// Scatter edges into dst-sorted order; precompute coefficient.
__global__ void k_scatter(const int* __restrict__ src, const int* __restrict__ dst,
                          const float* __restrict__ dinv,
                          int* __restrict__ cur,
                          int* __restrict__ srcs, float* __restrict__ coefs) {
    int e = blockIdx.x * blockDim.x + threadIdx.x;
    if (e >= NE) return;
    int s = src[e], d = dst[e];
    int pos = atomicAdd(&cur[d], 1);
    srcs[pos] = s;
    coefs[pos] = dinv[s] * dinv[d];
}

// aggX[n][f] = x[n][f]*dinv[n]^2 + sum_{p in [off[n],cur[n])} x[srcs[p]][f]*coefs[p]
// 256 threads = 2 nodes x 128 features. NN even -> no bounds check.
__global__ void k_gather(const float* __restrict__ x, const float* __restrict__ dinv,
                         const int* __restrict__ off, const int* __restrict__ cur,
                         const int* __restrict__ srcs, const float* __restrict__ coefs,
                         float* __restrict__ aggX) {
    int n = blockIdx.x * 2 + (threadIdx.x >> 7);
    int f = threadIdx.x & 127;
    float dv = dinv[n];
    float acc = x[(size_t)n * HD + f] * dv * dv;
    int p1 = cur[n];
    for (int p = off[n]; p < p1; ++p)
        acc += x[(size_t)srcs[p] * HD + f] * coefs[p];
    aggX[(size_t)n * HD + f] = acc;
}

// Fused: z[n] = relu(aggX[n]@W1 + b1) @ W2 ; agg2[n] = z[n]*dinv[n]^2
// Block: 256 threads, 32 nodes. LDS: W1 64KB + x-tile(transposed) 16KB.
__global__ __launch_bounds__(256, 1) void k_gcn_fused(
    const float* __restrict__ aggX, const float* __restrict__ W1,
    const float* __restrict__ b1, const float* __restrict__ W2,
    const float* __restrict__ dinv,
    float* __restrict__ z, float* __restrict__ agg2) {
    __shared__ float Wl[HD * HD];     // Wl[k*128+f]
    __shared__ float xs[HD][32];      // xs[k][node]
    int tid = threadIdx.x;
    int n0 = blockIdx.x * 32;

    {
        const float4* ws = (const float4*)W1;
        float4* wd = (float4*)Wl;
        for (int i = tid; i < HD * HD / 4; i += 256) wd[i] = ws[i];
    }
    {
        int n = tid & 31;
        int kq0 = tid >> 5;
        const float4* xsrc = (const float4*)(aggX + (size_t)(n0 + n) * HD);
#pragma unroll
        for (int j = 0; j < 4; ++j) {
            int kq = kq0 + j * 8;
            float4 v = xsrc[kq];
            xs[kq * 4 + 0][n] = v.x;
            xs[kq * 4 + 1][n] = v.y;
            xs[kq * 4 + 2][n] = v.z;
            xs[kq * 4 + 3][n] = v.w;
        }
    }
    __syncthreads();

    int fq = tid & 31;
    int ng = tid >> 5;
    float acc[4][4] = {{0.f}};
#pragma unroll 8
    for (int k = 0; k < HD; ++k) {
        float4 xv = *(const float4*)&xs[k][ng * 4];
        float4 wv = *(const float4*)&Wl[k * HD + fq * 4];
        acc[0][0] += xv.x * wv.x; acc[0][1] += xv.x * wv.y;
        acc[0][2] += xv.x * wv.z; acc[0][3] += xv.x * wv.w;
        acc[1][0] += xv.y * wv.x; acc[1][1] += xv.y * wv.y;
        acc[1][2] += xv.y * wv.z; acc[1][3] += xv.y * wv.w;
        acc[2][0] += xv.z * wv.x; acc[2][1] += xv.z * wv.y;
        acc[2][2] += xv.z * wv.z; acc[2][3] += xv.z * wv.w;
        acc[3][0] += xv.w * wv.x; acc[3][1] += xv.w * wv.y;
        acc[3][2] += xv.w * wv.z; acc[3][3] += xv.w * wv.w;
    }

    int f0 = fq * 4;
    float4 bb = *(const float4*)&b1[f0];
    float4 w2 = *(const float4*)&W2[f0];
    float part[4];
#pragma unroll
    for (int i = 0; i < 4; ++i) {
        part[i] = fmaxf(acc[i][0] + bb.x, 0.f) * w2.x
                + fmaxf(acc[i][1] + bb.y, 0.f) * w2.y
                + fmaxf(acc[i][2] + bb.z, 0.f) * w2.z
                + fmaxf(acc[i][3] + bb.w, 0.f) * w2.w;
    }
#pragma unroll
    for (int o = 16; o > 0; o >>= 1) {
#pragma unroll
        for (int i = 0; i < 4; ++i) part[i] += __shfl_down(part[i], o, 32);
    }
    if (fq == 0) {
#pragma unroll
        for (int i = 0; i < 4; ++i) {
            int n = n0 + ng * 4 + i;
            float dv = dinv[n];
            z[n] = part[i];
            agg2[n] = part[i] * dv * dv;
        }
    }
}

// agg2[dst] += z[src]*dinv[src]*dinv[dst]  (scalar, low traffic)
__global__ void k_edge2(const float* __restrict__ z, const float* __restrict__ dinv,
                        const int* __restrict__ src, const int* __restrict__ dst,
                        float* __restrict__ agg2) {
    int e = blockIdx.x * blockDim.x + threadIdx.x;
    if (e >= NE) return;
    int s = src[e], d = dst[e];
    atomicAdd(&agg2[d], z[s] * dinv[s] * dinv[d]);
}

// y[batch[n]] += agg2[n] + b2
__global__ void k_final(const float* __restrict__ agg2, const float* __restrict__ b2,
                        const int* __restrict__ batch, float* __restrict__ y) {
    int n = blockIdx.x * blockDim.x + threadIdx.x;
    if (n >= NN) return;
    atomicAdd(&y[batch[n]], agg2[n] + b2[0]);
}

extern "C" void kernel_launch(void* const* d_in, const int* in_sizes, int n_in,
                              void* d_out, int out_size, void* d_ws, size_t ws_size,
                              hipStream_t stream) {
    const int*   tok   = (const int*)d_in[0];
    const float* pe    = (const float*)d_in[1];
    const int*   ei    = (const int*)d_in[2];
    const int*   vei   = (const int*)d_in[3];
    const int*   batch = (const int*)d_in[4];
    const float* embed = (const float*)d_in[5];
    const float* Wt    = (const float*)d_in[6];
    const float* bt    = (const float*)d_in[7];
    const float* W1    = (const float*)d_in[8];
    const float* b1    = (const float*)d_in[9];
    const float* W2    = (const float*)d_in[10];
    const float* b2    = (const float*)d_in[11];
    const float* Wv1   = (const float*)d_in[12];
    const float* bv1   = (const float*)d_in[13];
    const float* Wv2   = (const float*)d_in[14];
    const float* bv2   = (const float*)d_in[15];

    float* y = (float*)d_out;       // [NG]
    float* x = y + NG;              // [NN*HD], output 1

    float* aggX  = (float*)d_ws;                 // [NN*HD]
    float* dinv  = aggX  + (size_t)NN * HD;      // [NN]
    float* z     = dinv  + NN;                   // [NN]
    float* agg2  = z     + NN;                   // [NN]
    int*   cnt   = (int*)(agg2 + NN);            // [NN]
    int*   off   = cnt   + NN;                   // [NN]
    int*   cur   = off   + NN;                   // [NN]
    int*   srcs  = cur   + NN;                   // [NE]
    float* coefs = (float*)(srcs + NE);          // [NE]
    int*   bsum  = (int*)(coefs + NE);           // [512]

    hipMemsetAsync(y, 0, NG * sizeof(float), stream);
    k_compute_x<<<(NN * HD + 255) / 256, 256, 0, stream>>>(tok, pe, embed, Wt, bt, x);

    for (int br = 0; br < 2; ++br) {
        const int* src = br ? vei : ei;
        const int* dst = src + NE;
        const float* Wa = br ? Wv1 : W1;
        const float* ba = br ? bv1 : b1;
        const float* Wb = br ? Wv2 : W2;
        const float* bb = br ? bv2 : b2;

        hipMemsetAsync(cnt, 0, NN * sizeof(int), stream);
        k_deg<<<(NE + 255) / 256, 256, 0, stream>>>(dst, cnt);
        k_dinv<<<(NN + 255) / 256, 256, 0, stream>>>(cnt, dinv);
        k_scan1<<<NB_SCAN, 256, 0, stream>>>(cnt, off, bsum);
        k_scan2<<<1, 512, 0, stream>>>(bsum);
        k_scan3<<<NB_SCAN, 256, 0, stream>>>(off, bsum, cur);
        k_scatter<<<(NE + 255) / 256, 256, 0, stream>>>(src, dst, dinv, cur, srcs, coefs);
        k_gather<<<NN / 2, 256, 0, stream>>>(x, dinv, off, cur, srcs, coefs, aggX);
        k_gcn_fused<<<NN / 32, 256, 0, stream>>>(aggX, Wa, ba, Wb, dinv, z, agg2);
        k_edge2<<<(NE + 255) / 256, 256, 0, stream>>>(z, dinv, src, dst, agg2);
        k_final<<<(NN + 255) / 256, 256, 0, stream>>>(agg2, bb, batch, y);
    }
}

// Round 4
// 317.987 us; speedup vs baseline: 3.5361x; 1.5658x over previous
//
#include <hip/hip_runtime.h>

#define NN 100000
#define NE 220000
#define HD 128
#define NG 4096
#define NPE 5
#define NB_SCAN ((NN + 255) / 256)   // 391

typedef unsigned int uint;
typedef unsigned short ushort;
typedef __attribute__((ext_vector_type(8))) short bf16x8;
typedef __attribute__((ext_vector_type(4))) float f32x4;

__device__ __forceinline__ float bf2f(uint u16) {
    return __uint_as_float(u16 << 16);
}
__device__ __forceinline__ ushort f2bf(float f) {
    uint u = __float_as_uint(f);
    u += 0x7fffu + ((u >> 16) & 1u);   // RNE
    return (ushort)(u >> 16);
}

// x[n][f] = embed[tok[n]][f] + bt[f] + sum_k pe[n][k]*Wt[k][f]; also bf16 copy
__global__ void k_compute_x(const int* __restrict__ tok,
                            const float* __restrict__ pe,
                            const float* __restrict__ embed,
                            const float* __restrict__ Wt,
                            const float* __restrict__ bt,
                            float* __restrict__ x, ushort* __restrict__ xb) {
    int idx = blockIdx.x * blockDim.x + threadIdx.x;
    if (idx >= NN * HD) return;
    int n = idx >> 7, f = idx & 127;
    float acc = embed[tok[n] * HD + f] + bt[f];
    const float* pen = pe + n * NPE;
#pragma unroll
    for (int k = 0; k < NPE; ++k) acc += pen[k] * Wt[k * HD + f];
    x[idx] = acc;
    xb[idx] = f2bf(acc);
}

// Wcat_bf16[f][k], f in [0,256): f<128 -> W1[k][f], else Wv1[k][f-128]
__global__ void k_prep_w(const float* __restrict__ W1, const float* __restrict__ Wv1,
                         ushort* __restrict__ Wt) {
    int t = blockIdx.x * 256 + threadIdx.x;     // 32768
    int f = t >> 7, k = t & 127;
    const float* W = (f < HD) ? W1 : Wv1;
    Wt[t] = f2bf(W[k * HD + (f & 127)]);
}

// H = xb @ [W1|Wv1]^T-staged, bf16 MFMA 16x16x32. Block: 256 thr, 32 nodes,
// 128 feats (one half selected by fh). LDS rows padded +8 ushorts.
#define LDP 136
__global__ __launch_bounds__(256) void k_gemm(const ushort* __restrict__ xb,
                                              const ushort* __restrict__ Wt,
                                              ushort* __restrict__ H) {
    __shared__ ushort Ws[128 * LDP];
    __shared__ ushort As[32 * LDP];
    int bi = blockIdx.x;
    int fh = bi / 3125;
    int n0 = (bi % 3125) * 32;
    int tid = threadIdx.x;
    {   // stage W half [128][128] -> padded
        const uint4* src = (const uint4*)(Wt + (size_t)fh * 128 * 128);
        uint4* dst = (uint4*)Ws;
        for (int i = tid; i < 2048; i += 256) dst[(i >> 4) * 17 + (i & 15)] = src[i];
    }
    {   // stage A tile [32][128] -> padded
        const uint4* src = (const uint4*)(xb + (size_t)n0 * HD);
        uint4* dst = (uint4*)As;
        for (int i = tid; i < 512; i += 256) dst[(i >> 4) * 17 + (i & 15)] = src[i];
    }
    __syncthreads();
    int w = tid >> 6, lane = tid & 63;
    int m = lane & 15, quad = lane >> 4;
    f32x4 acc[2][2] = {};
#pragma unroll
    for (int kc = 0; kc < 4; ++kc) {
        int k0 = kc * 32 + quad * 8;
        bf16x8 a0 = *(const bf16x8*)&As[(0 + m) * LDP + k0];
        bf16x8 a1 = *(const bf16x8*)&As[(16 + m) * LDP + k0];
        bf16x8 b0 = *(const bf16x8*)&Ws[(w * 32 + m) * LDP + k0];
        bf16x8 b1 = *(const bf16x8*)&Ws[(w * 32 + 16 + m) * LDP + k0];
        acc[0][0] = __builtin_amdgcn_mfma_f32_16x16x32_bf16(a0, b0, acc[0][0], 0, 0, 0);
        acc[0][1] = __builtin_amdgcn_mfma_f32_16x16x32_bf16(a0, b1, acc[0][1], 0, 0, 0);
        acc[1][0] = __builtin_amdgcn_mfma_f32_16x16x32_bf16(a1, b0, acc[1][0], 0, 0, 0);
        acc[1][1] = __builtin_amdgcn_mfma_f32_16x16x32_bf16(a1, b1, acc[1][1], 0, 0, 0);
    }
    // D: col(feat-in-tile)=lane&15, row(node-in-tile)=quad*4+reg
#pragma unroll
    for (int nt = 0; nt < 2; ++nt)
#pragma unroll
        for (int ft = 0; ft < 2; ++ft)
#pragma unroll
            for (int r = 0; r < 4; ++r) {
                int n = n0 + nt * 16 + quad * 4 + r;
                int f = fh * 128 + w * 32 + ft * 16 + m;
                H[(size_t)n * 256 + f] = f2bf(acc[nt][ft][r]);
            }
}

// degree count, both branches
__global__ void k_deg(const int* __restrict__ ei, const int* __restrict__ vei,
                      int* __restrict__ cnt) {
    int t = blockIdx.x * blockDim.x + threadIdx.x;
    if (t >= 2 * NE) return;
    int br = t >= NE;
    int e = t - br * NE;
    const int* S = br ? vei : ei;
    atomicAdd(&cnt[br * NN + S[NE + e]], 1);
}

// per-block exclusive scan + dinv
__global__ void k_scan1(const int* __restrict__ cnt, int* __restrict__ off,
                        int* __restrict__ bsum, float* __restrict__ dinv) {
    __shared__ int s[256];
    int br = blockIdx.x / NB_SCAN;
    int blk = blockIdx.x % NB_SCAN;
    int tid = threadIdx.x;
    int i = blk * 256 + tid;
    int v = (i < NN) ? cnt[br * NN + i] : 0;
    if (i < NN) dinv[br * NN + i] = rsqrtf((float)v + 1.0f);
    s[tid] = v;
    __syncthreads();
    for (int d = 1; d < 256; d <<= 1) {
        int t = (tid >= d) ? s[tid - d] : 0;
        __syncthreads();
        s[tid] += t;
        __syncthreads();
    }
    if (i < NN) off[br * NN + i] = s[tid] - v;
    if (tid == 255) bsum[br * 512 + blk] = s[255];
}

__global__ void k_scan2(int* __restrict__ bsum) {
    __shared__ int s[512];
    int br = blockIdx.x;
    int tid = threadIdx.x;
    int v = (tid < NB_SCAN) ? bsum[br * 512 + tid] : 0;
    s[tid] = v;
    __syncthreads();
    for (int d = 1; d < 512; d <<= 1) {
        int t = (tid >= d) ? s[tid - d] : 0;
        __syncthreads();
        s[tid] += t;
        __syncthreads();
    }
    if (tid < NB_SCAN) bsum[br * 512 + tid] = s[tid] - v;
}

__global__ void k_scan3(int* __restrict__ off, const int* __restrict__ bsum,
                        int* __restrict__ cur) {
    int br = blockIdx.x / NB_SCAN;
    int blk = blockIdx.x % NB_SCAN;
    int i = blk * 256 + threadIdx.x;
    if (i < NN) {
        int o = off[br * NN + i] + bsum[br * 512 + blk];
        off[br * NN + i] = o;
        cur[br * NN + i] = o;
    }
}

__global__ void k_scatter(const int* __restrict__ ei, const int* __restrict__ vei,
                          const float* __restrict__ dinv, int* __restrict__ cur,
                          int* __restrict__ srcs, float* __restrict__ coefs) {
    int t = blockIdx.x * blockDim.x + threadIdx.x;
    if (t >= 2 * NE) return;
    int br = t >= NE;
    int e = t - br * NE;
    const int* S = br ? vei : ei;
    int s = S[e], d = S[NE + e];
    int pos = atomicAdd(&cur[br * NN + d], 1);
    srcs[br * NE + pos] = s;
    coefs[br * NE + pos] = dinv[br * NN + s] * dinv[br * NN + d];
}

// Fused gather + layer-1 epilogue: one wave per (branch, node).
// z[br][n] = sum_f relu( (A_norm H_br)[n][f] + b1[f] ) * W2[f]
__global__ void k_gather_ep(const ushort* __restrict__ H, const float* __restrict__ dinv,
                            const int* __restrict__ off, const int* __restrict__ cur,
                            const int* __restrict__ srcs, const float* __restrict__ coefs,
                            const float* __restrict__ b1, const float* __restrict__ bv1,
                            const float* __restrict__ W2, const float* __restrict__ Wv2,
                            float* __restrict__ z) {
    int b = blockIdx.x;                 // 0 .. 2*NN/4-1
    int br = b >= (NN / 4);
    int nb = b - br * (NN / 4);
    int n = nb * 4 + (threadIdx.x >> 6);
    int lane = threadIdx.x & 63;

    float dv = dinv[br * NN + n];
    uint u = ((const uint*)(H + (size_t)n * 256 + br * 128))[lane];
    float c = dv * dv;
    float a0 = bf2f(u & 0xffffu) * c;
    float a1 = bf2f(u >> 16) * c;

    int p0 = off[br * NN + n], p1 = cur[br * NN + n];
    for (int p = p0; p < p1; ++p) {
        int s = srcs[br * NE + p];
        float cf = coefs[br * NE + p];
        uint us = ((const uint*)(H + (size_t)s * 256 + br * 128))[lane];
        a0 += bf2f(us & 0xffffu) * cf;
        a1 += bf2f(us >> 16) * cf;
    }
    const float* bb = br ? bv1 : b1;
    const float* ww = br ? Wv2 : W2;
    int f0 = lane * 2;
    float part = fmaxf(a0 + bb[f0], 0.f) * ww[f0]
               + fmaxf(a1 + bb[f0 + 1], 0.f) * ww[f0 + 1];
#pragma unroll
    for (int o = 32; o > 0; o >>= 1) part += __shfl_down(part, o, 64);
    if (lane == 0) z[br * NN + n] = part;
}

// Layer-2 aggregation via same CSR + batch reduction, both branches.
__global__ void k_final2(const float* __restrict__ z, const float* __restrict__ dinv,
                         const int* __restrict__ off, const int* __restrict__ cur,
                         const int* __restrict__ srcs, const float* __restrict__ coefs,
                         const float* __restrict__ b2, const float* __restrict__ bv2,
                         const int* __restrict__ batch, float* __restrict__ y) {
    int t = blockIdx.x * blockDim.x + threadIdx.x;
    if (t >= 2 * NN) return;
    int br = t >= NN;
    int n = t - br * NN;
    float dv = dinv[br * NN + n];
    float acc = z[br * NN + n] * dv * dv;
    int p1 = cur[br * NN + n];
    for (int p = off[br * NN + n]; p < p1; ++p)
        acc += coefs[br * NE + p] * z[br * NN + srcs[br * NE + p]];
    acc += br ? bv2[0] : b2[0];
    atomicAdd(&y[batch[n]], acc);
}

extern "C" void kernel_launch(void* const* d_in, const int* in_sizes, int n_in,
                              void* d_out, int out_size, void* d_ws, size_t ws_size,
                              hipStream_t stream) {
    const int*   tok   = (const int*)d_in[0];
    const float* pe    = (const float*)d_in[1];
    const int*   ei    = (const int*)d_in[2];
    const int*   vei   = (const int*)d_in[3];
    const int*   batch = (const int*)d_in[4];
    const float* embed = (const float*)d_in[5];
    const float* Wtr   = (const float*)d_in[6];
    const float* bt    = (const float*)d_in[7];
    const float* W1    = (const float*)d_in[8];
    const float* b1    = (const float*)d_in[9];
    const float* W2    = (const float*)d_in[10];
    const float* b2    = (const float*)d_in[11];
    const float* Wv1   = (const float*)d_in[12];
    const float* bv1   = (const float*)d_in[13];
    const float* Wv2   = (const float*)d_in[14];
    const float* bv2   = (const float*)d_in[15];

    float* y = (float*)d_out;       // [NG]
    float* x = y + NG;              // [NN*HD], output 1

    char* w = (char*)d_ws;
    ushort* xb   = (ushort*)w;               w += (size_t)NN * HD * 2;   // 25.6MB
    ushort* H    = (ushort*)w;               w += (size_t)NN * 256 * 2;  // 51.2MB
    ushort* Wcat = (ushort*)w;               w += 256 * 128 * 2;
    float*  dinv = (float*)w;                w += 2 * NN * 4;
    float*  z    = (float*)w;                w += 2 * NN * 4;
    int*    cnt  = (int*)w;                  w += 2 * NN * 4;
    int*    off  = (int*)w;                  w += 2 * NN * 4;
    int*    cur  = (int*)w;                  w += 2 * NN * 4;
    int*    srcs = (int*)w;                  w += 2 * NE * 4;
    float*  coefs= (float*)w;                w += 2 * NE * 4;
    int*    bsum = (int*)w;                  w += 2 * 512 * 4;

    hipMemsetAsync(y, 0, NG * sizeof(float), stream);
    hipMemsetAsync(cnt, 0, 2 * NN * sizeof(int), stream);

    k_compute_x<<<(NN * HD + 255) / 256, 256, 0, stream>>>(tok, pe, embed, Wtr, bt, x, xb);
    k_prep_w<<<128, 256, 0, stream>>>(W1, Wv1, Wcat);
    k_gemm<<<2 * 3125, 256, 0, stream>>>(xb, Wcat, H);
    k_deg<<<(2 * NE + 255) / 256, 256, 0, stream>>>(ei, vei, cnt);
    k_scan1<<<2 * NB_SCAN, 256, 0, stream>>>(cnt, off, bsum, dinv);
    k_scan2<<<2, 512, 0, stream>>>(bsum);
    k_scan3<<<2 * NB_SCAN, 256, 0, stream>>>(off, bsum, cur);
    k_scatter<<<(2 * NE + 255) / 256, 256, 0, stream>>>(ei, vei, dinv, cur, srcs, coefs);
    k_gather_ep<<<2 * (NN / 4), 256, 0, stream>>>(H, dinv, off, cur, srcs, coefs,
                                                  b1, bv1, W2, Wv2, z);
    k_final2<<<(2 * NN + 255) / 256, 256, 0, stream>>>(z, dinv, off, cur, srcs, coefs,
                                                       b2, bv2, batch, y);
}

// Round 5
// 290.155 us; speedup vs baseline: 3.8753x; 1.0959x over previous
//
#include <hip/hip_runtime.h>

#define NN 100000
#define NE 220000
#define HD 128
#define NG 4096
#define NPE 5
#define NB_SCAN ((NN + 255) / 256)   // 391

typedef unsigned int uint;
typedef unsigned short ushort;
typedef __attribute__((ext_vector_type(8))) short bf16x8;
typedef __attribute__((ext_vector_type(4))) float f32x4;

__device__ __forceinline__ float bf2f(uint u16) {
    return __uint_as_float(u16 << 16);
}
__device__ __forceinline__ ushort f2bf(float f) {
    uint u = __float_as_uint(f);
    u += 0x7fffu + ((u >> 16) & 1u);   // RNE
    return (ushort)(u >> 16);
}

// x[n][f] = embed[tok[n]][f] + bt[f] + sum_k pe[n][k]*Wt[k][f]; also bf16 copy
__global__ void k_compute_x(const int* __restrict__ tok,
                            const float* __restrict__ pe,
                            const float* __restrict__ embed,
                            const float* __restrict__ Wt,
                            const float* __restrict__ bt,
                            float* __restrict__ x, ushort* __restrict__ xb) {
    int idx = blockIdx.x * blockDim.x + threadIdx.x;
    if (idx >= NN * HD) return;
    int n = idx >> 7, f = idx & 127;
    float acc = embed[tok[n] * HD + f] + bt[f];
    const float* pen = pe + n * NPE;
#pragma unroll
    for (int k = 0; k < NPE; ++k) acc += pen[k] * Wt[k * HD + f];
    x[idx] = acc;
    xb[idx] = f2bf(acc);
}

// Wcat_bf16[f][k], f in [0,256): f<128 -> W1[k][f], else Wv1[k][f-128]
__global__ void k_prep_w(const float* __restrict__ W1, const float* __restrict__ Wv1,
                         ushort* __restrict__ Wt) {
    int t = blockIdx.x * 256 + threadIdx.x;     // 32768
    int f = t >> 7, k = t & 127;
    const float* W = (f < HD) ? W1 : Wv1;
    Wt[t] = f2bf(W[k * HD + (f & 127)]);
}

// H[n][f] (f in [0,256)) = xb[n] @ Wcat[f]. 128-node x 128-feat-half tiles.
// MFMA operands swapped: A=W (m=f), B=x (n=node) -> D[f][n]: lane col = node,
// rows quad*4+reg = 4 consecutive f -> pack uint2, one 8B store per tile.
#define LDP 136
__global__ __launch_bounds__(256) void k_gemm(const ushort* __restrict__ xb,
                                              const ushort* __restrict__ Wt,
                                              ushort* __restrict__ H) {
    __shared__ ushort Ws[128 * LDP];
    __shared__ ushort As[128 * LDP];
    int bi = blockIdx.x;
    int fh = bi & 1;
    int n0 = (bi >> 1) * 128;
    int tid = threadIdx.x;
    {   // stage W half [128][128]
        const uint4* src = (const uint4*)(Wt + (size_t)fh * 128 * 128);
        uint4* dst = (uint4*)Ws;
        for (int i = tid; i < 2048; i += 256) dst[(i >> 4) * 17 + (i & 15)] = src[i];
    }
    {   // stage A tile [128][128] with bounds
        uint4* dst = (uint4*)As;
        for (int i = tid; i < 2048; i += 256) {
            int n = n0 + (i >> 4);
            uint4 v = {0u, 0u, 0u, 0u};
            if (n < NN) v = ((const uint4*)(xb + (size_t)n * HD))[i & 15];
            dst[(i >> 4) * 17 + (i & 15)] = v;
        }
    }
    __syncthreads();
    int w = tid >> 6, lane = tid & 63;
    int m = lane & 15, quad = lane >> 4;
    f32x4 acc[2][8] = {};
#pragma unroll
    for (int kc = 0; kc < 4; ++kc) {
        int k0 = kc * 32 + quad * 8;
        bf16x8 xf[2], wf[8];
#pragma unroll
        for (int nt = 0; nt < 2; ++nt)
            xf[nt] = *(const bf16x8*)&As[((w * 2 + nt) * 16 + m) * LDP + k0];
#pragma unroll
        for (int ft = 0; ft < 8; ++ft)
            wf[ft] = *(const bf16x8*)&Ws[(ft * 16 + m) * LDP + k0];
#pragma unroll
        for (int nt = 0; nt < 2; ++nt)
#pragma unroll
            for (int ft = 0; ft < 8; ++ft)
                acc[nt][ft] = __builtin_amdgcn_mfma_f32_16x16x32_bf16(
                    wf[ft], xf[nt], acc[nt][ft], 0, 0, 0);
    }
#pragma unroll
    for (int nt = 0; nt < 2; ++nt) {
        int n = n0 + (w * 2 + nt) * 16 + m;
        if (n >= NN) continue;
#pragma unroll
        for (int ft = 0; ft < 8; ++ft) {
            f32x4 a = acc[nt][ft];
            uint2 pk;
            pk.x = (uint)f2bf(a[0]) | ((uint)f2bf(a[1]) << 16);
            pk.y = (uint)f2bf(a[2]) | ((uint)f2bf(a[3]) << 16);
            *(uint2*)&H[(size_t)n * 256 + fh * 128 + ft * 16 + quad * 4] = pk;
        }
    }
}

// degree count, both branches
__global__ void k_deg(const int* __restrict__ ei, const int* __restrict__ vei,
                      int* __restrict__ cnt) {
    int t = blockIdx.x * blockDim.x + threadIdx.x;
    if (t >= 2 * NE) return;
    int br = t >= NE;
    int e = t - br * NE;
    const int* S = br ? vei : ei;
    atomicAdd(&cnt[br * NN + S[NE + e]], 1);
}

// per-block exclusive scan + dinv
__global__ void k_scan1(const int* __restrict__ cnt, int* __restrict__ off,
                        int* __restrict__ bsum, float* __restrict__ dinv) {
    __shared__ int s[256];
    int br = blockIdx.x / NB_SCAN;
    int blk = blockIdx.x % NB_SCAN;
    int tid = threadIdx.x;
    int i = blk * 256 + tid;
    int v = (i < NN) ? cnt[br * NN + i] : 0;
    if (i < NN) dinv[br * NN + i] = rsqrtf((float)v + 1.0f);
    s[tid] = v;
    __syncthreads();
    for (int d = 1; d < 256; d <<= 1) {
        int t = (tid >= d) ? s[tid - d] : 0;
        __syncthreads();
        s[tid] += t;
        __syncthreads();
    }
    if (i < NN) off[br * NN + i] = s[tid] - v;
    if (tid == 255) bsum[br * 512 + blk] = s[255];
}

__global__ void k_scan2(int* __restrict__ bsum) {
    __shared__ int s[512];
    int br = blockIdx.x;
    int tid = threadIdx.x;
    int v = (tid < NB_SCAN) ? bsum[br * 512 + tid] : 0;
    s[tid] = v;
    __syncthreads();
    for (int d = 1; d < 512; d <<= 1) {
        int t = (tid >= d) ? s[tid - d] : 0;
        __syncthreads();
        s[tid] += t;
        __syncthreads();
    }
    if (tid < NB_SCAN) bsum[br * 512 + tid] = s[tid] - v;
}

__global__ void k_scan3(int* __restrict__ off, const int* __restrict__ bsum,
                        int* __restrict__ cur) {
    int br = blockIdx.x / NB_SCAN;
    int blk = blockIdx.x % NB_SCAN;
    int i = blk * 256 + threadIdx.x;
    if (i < NN) {
        int o = off[br * NN + i] + bsum[br * 512 + blk];
        off[br * NN + i] = o;
        cur[br * NN + i] = o;
    }
}

__global__ void k_scatter(const int* __restrict__ ei, const int* __restrict__ vei,
                          const float* __restrict__ dinv, int* __restrict__ cur,
                          int* __restrict__ srcs, float* __restrict__ coefs) {
    int t = blockIdx.x * blockDim.x + threadIdx.x;
    if (t >= 2 * NE) return;
    int br = t >= NE;
    int e = t - br * NE;
    const int* S = br ? vei : ei;
    int s = S[e], d = S[NE + e];
    int pos = atomicAdd(&cur[br * NN + d], 1);
    srcs[br * NE + pos] = s;
    coefs[br * NE + pos] = dinv[br * NN + s] * dinv[br * NN + d];
}

// Fused gather + layer-1 epilogue. 2 nodes per wave: half=lane>>5, l=lane&31,
// lane covers feats 4l..4l+3 via uint2 (one instr loads both nodes' rows).
// Edge loop manually unrolled x2 for MLP.
__global__ void k_gather_ep(const ushort* __restrict__ H, const float* __restrict__ dinv,
                            const int* __restrict__ off, const int* __restrict__ cur,
                            const int* __restrict__ srcs, const float* __restrict__ coefs,
                            const float* __restrict__ b1, const float* __restrict__ bv1,
                            const float* __restrict__ W2, const float* __restrict__ Wv2,
                            float* __restrict__ z) {
    int wid = threadIdx.x >> 6;
    int lane = threadIdx.x & 63;
    int half = lane >> 5;
    int l = lane & 31;
    int task = blockIdx.x * 8 + wid * 2 + half;   // 2*NN tasks, br uniform per wave
    int br = task >= NN;
    int n = task - br * NN;

    const int* sr = srcs + br * NE;
    const float* cf = coefs + br * NE;
    size_t hoff = (size_t)br * 128;

    float dv = dinv[br * NN + n];
    uint2 u = *(const uint2*)(H + (size_t)n * 256 + hoff + l * 4);
    float c = dv * dv;
    float a0 = bf2f(u.x & 0xffffu) * c, a1 = bf2f(u.x >> 16) * c;
    float a2 = bf2f(u.y & 0xffffu) * c, a3 = bf2f(u.y >> 16) * c;

    int p = off[br * NN + n], p1 = cur[br * NN + n];
    for (; p + 1 < p1; p += 2) {
        int s0 = sr[p], s1 = sr[p + 1];
        float c0 = cf[p], c1 = cf[p + 1];
        uint2 v0 = *(const uint2*)(H + (size_t)s0 * 256 + hoff + l * 4);
        uint2 v1 = *(const uint2*)(H + (size_t)s1 * 256 + hoff + l * 4);
        a0 += bf2f(v0.x & 0xffffu) * c0; a1 += bf2f(v0.x >> 16) * c0;
        a2 += bf2f(v0.y & 0xffffu) * c0; a3 += bf2f(v0.y >> 16) * c0;
        a0 += bf2f(v1.x & 0xffffu) * c1; a1 += bf2f(v1.x >> 16) * c1;
        a2 += bf2f(v1.y & 0xffffu) * c1; a3 += bf2f(v1.y >> 16) * c1;
    }
    if (p < p1) {
        int s0 = sr[p];
        float c0 = cf[p];
        uint2 v0 = *(const uint2*)(H + (size_t)s0 * 256 + hoff + l * 4);
        a0 += bf2f(v0.x & 0xffffu) * c0; a1 += bf2f(v0.x >> 16) * c0;
        a2 += bf2f(v0.y & 0xffffu) * c0; a3 += bf2f(v0.y >> 16) * c0;
    }

    const float* bb = br ? bv1 : b1;
    const float* ww = br ? Wv2 : W2;
    float4 b4 = *(const float4*)&bb[l * 4];
    float4 w4 = *(const float4*)&ww[l * 4];
    float part = fmaxf(a0 + b4.x, 0.f) * w4.x + fmaxf(a1 + b4.y, 0.f) * w4.y
               + fmaxf(a2 + b4.z, 0.f) * w4.z + fmaxf(a3 + b4.w, 0.f) * w4.w;
#pragma unroll
    for (int o = 16; o > 0; o >>= 1) part += __shfl_down(part, o, 32);
    if (l == 0) z[br * NN + n] = part;
}

// Layer-2 aggregation via same CSR + batch reduction, both branches.
__global__ void k_final2(const float* __restrict__ z, const float* __restrict__ dinv,
                         const int* __restrict__ off, const int* __restrict__ cur,
                         const int* __restrict__ srcs, const float* __restrict__ coefs,
                         const float* __restrict__ b2, const float* __restrict__ bv2,
                         const int* __restrict__ batch, float* __restrict__ y) {
    int t = blockIdx.x * blockDim.x + threadIdx.x;
    if (t >= 2 * NN) return;
    int br = t >= NN;
    int n = t - br * NN;
    float dv = dinv[br * NN + n];
    float acc = z[br * NN + n] * dv * dv;
    int p1 = cur[br * NN + n];
    for (int p = off[br * NN + n]; p < p1; ++p)
        acc += coefs[br * NE + p] * z[br * NN + srcs[br * NE + p]];
    acc += br ? bv2[0] : b2[0];
    atomicAdd(&y[batch[n]], acc);
}

extern "C" void kernel_launch(void* const* d_in, const int* in_sizes, int n_in,
                              void* d_out, int out_size, void* d_ws, size_t ws_size,
                              hipStream_t stream) {
    const int*   tok   = (const int*)d_in[0];
    const float* pe    = (const float*)d_in[1];
    const int*   ei    = (const int*)d_in[2];
    const int*   vei   = (const int*)d_in[3];
    const int*   batch = (const int*)d_in[4];
    const float* embed = (const float*)d_in[5];
    const float* Wtr   = (const float*)d_in[6];
    const float* bt    = (const float*)d_in[7];
    const float* W1    = (const float*)d_in[8];
    const float* b1    = (const float*)d_in[9];
    const float* W2    = (const float*)d_in[10];
    const float* b2    = (const float*)d_in[11];
    const float* Wv1   = (const float*)d_in[12];
    const float* bv1   = (const float*)d_in[13];
    const float* Wv2   = (const float*)d_in[14];
    const float* bv2   = (const float*)d_in[15];

    float* y = (float*)d_out;       // [NG]
    float* x = y + NG;              // [NN*HD], output 1

    char* w = (char*)d_ws;
    ushort* xb   = (ushort*)w;               w += (size_t)NN * HD * 2;
    ushort* H    = (ushort*)w;               w += (size_t)NN * 256 * 2;
    ushort* Wcat = (ushort*)w;               w += 256 * 128 * 2;
    float*  dinv = (float*)w;                w += 2 * NN * 4;
    float*  z    = (float*)w;                w += 2 * NN * 4;
    int*    cnt  = (int*)w;                  w += 2 * NN * 4;
    int*    off  = (int*)w;                  w += 2 * NN * 4;
    int*    cur  = (int*)w;                  w += 2 * NN * 4;
    int*    srcs = (int*)w;                  w += 2 * NE * 4;
    float*  coefs= (float*)w;                w += 2 * NE * 4;
    int*    bsum = (int*)w;                  w += 2 * 512 * 4;

    hipMemsetAsync(y, 0, NG * sizeof(float), stream);
    hipMemsetAsync(cnt, 0, 2 * NN * sizeof(int), stream);

    k_compute_x<<<(NN * HD + 255) / 256, 256, 0, stream>>>(tok, pe, embed, Wtr, bt, x, xb);
    k_prep_w<<<128, 256, 0, stream>>>(W1, Wv1, Wcat);
    k_gemm<<<2 * ((NN + 127) / 128), 256, 0, stream>>>(xb, Wcat, H);
    k_deg<<<(2 * NE + 255) / 256, 256, 0, stream>>>(ei, vei, cnt);
    k_scan1<<<2 * NB_SCAN, 256, 0, stream>>>(cnt, off, bsum, dinv);
    k_scan2<<<2, 512, 0, stream>>>(bsum);
    k_scan3<<<2 * NB_SCAN, 256, 0, stream>>>(off, bsum, cur);
    k_scatter<<<(2 * NE + 255) / 256, 256, 0, stream>>>(ei, vei, dinv, cur, srcs, coefs);
    k_gather_ep<<<2 * NN / 8, 256, 0, stream>>>(H, dinv, off, cur, srcs, coefs,
                                                b1, bv1, W2, Wv2, z);
    k_final2<<<(2 * NN + 255) / 256, 256, 0, stream>>>(z, dinv, off, cur, srcs, coefs,
                                                       b2, bv2, batch, y);
}

// Round 6
// 268.725 us; speedup vs baseline: 4.1843x; 1.0797x over previous
//
#include <hip/hip_runtime.h>

#define NN 100000
#define NE 220000
#define HD 128
#define NG 4096
#define NPE 5
#define NB_SCAN ((NN + 255) / 256)   // 391
#define NBX ((NN * HD) / 256)        // 50000 (exact)
#define NBW 128                      // prep_w blocks
#define NBD ((2 * NE + 255) / 256)   // 1719

typedef unsigned int uint;
typedef unsigned short ushort;
typedef __attribute__((ext_vector_type(8))) short bf16x8;
typedef __attribute__((ext_vector_type(4))) float f32x4;

__device__ __forceinline__ float bf2f(uint u16) {
    return __uint_as_float(u16 << 16);
}
__device__ __forceinline__ ushort f2bf(float f) {
    uint u = __float_as_uint(f);
    u += 0x7fffu + ((u >> 16) & 1u);   // RNE
    return (ushort)(u >> 16);
}

// Fused front: [0,NBX) compute x/xb; [NBX,NBX+NBW) build Wcat; rest: degree.
__global__ void k_front(const int* __restrict__ tok, const float* __restrict__ pe,
                        const float* __restrict__ embed, const float* __restrict__ Wtr,
                        const float* __restrict__ bt,
                        float* __restrict__ x, ushort* __restrict__ xb,
                        const float* __restrict__ W1, const float* __restrict__ Wv1,
                        ushort* __restrict__ Wcat,
                        const int* __restrict__ ei, const int* __restrict__ vei,
                        int* __restrict__ cnt) {
    int b = blockIdx.x;
    if (b < NBX) {
        int idx = b * 256 + threadIdx.x;
        int n = idx >> 7, f = idx & 127;
        float acc = embed[tok[n] * HD + f] + bt[f];
        const float* pen = pe + n * NPE;
#pragma unroll
        for (int k = 0; k < NPE; ++k) acc += pen[k] * Wtr[k * HD + f];
        x[idx] = acc;
        xb[idx] = f2bf(acc);
    } else if (b < NBX + NBW) {
        int t = (b - NBX) * 256 + threadIdx.x;   // 32768
        int f = t >> 7, k = t & 127;
        const float* W = (f < HD) ? W1 : Wv1;
        Wcat[t] = f2bf(W[k * HD + (f & 127)]);
    } else {
        int t = (b - NBX - NBW) * 256 + threadIdx.x;
        if (t < 2 * NE) {
            int br = t >= NE;
            int e = t - br * NE;
            const int* S = br ? vei : ei;
            atomicAdd(&cnt[br * NN + S[NE + e]], 1);
        }
    }
}

// H[n][f] (f in [0,256)) = xb[n] @ Wcat[f]. 128-node x 128-feat-half tiles.
// A=W (m=f), B=x (n=node) -> D rows = 4 consecutive f -> 8B packed stores.
#define LDP 136
__global__ __launch_bounds__(256) void k_gemm(const ushort* __restrict__ xb,
                                              const ushort* __restrict__ Wt,
                                              ushort* __restrict__ H) {
    __shared__ ushort Ws[128 * LDP];
    __shared__ ushort As[128 * LDP];
    int bi = blockIdx.x;
    int fh = bi & 1;
    int n0 = (bi >> 1) * 128;
    int tid = threadIdx.x;
    {
        const uint4* src = (const uint4*)(Wt + (size_t)fh * 128 * 128);
        uint4* dst = (uint4*)Ws;
        for (int i = tid; i < 2048; i += 256) dst[(i >> 4) * 17 + (i & 15)] = src[i];
    }
    {
        uint4* dst = (uint4*)As;
        for (int i = tid; i < 2048; i += 256) {
            int n = n0 + (i >> 4);
            uint4 v = {0u, 0u, 0u, 0u};
            if (n < NN) v = ((const uint4*)(xb + (size_t)n * HD))[i & 15];
            dst[(i >> 4) * 17 + (i & 15)] = v;
        }
    }
    __syncthreads();
    int w = tid >> 6, lane = tid & 63;
    int m = lane & 15, quad = lane >> 4;
    f32x4 acc[2][8] = {};
#pragma unroll
    for (int kc = 0; kc < 4; ++kc) {
        int k0 = kc * 32 + quad * 8;
        bf16x8 xf[2], wf[8];
#pragma unroll
        for (int nt = 0; nt < 2; ++nt)
            xf[nt] = *(const bf16x8*)&As[((w * 2 + nt) * 16 + m) * LDP + k0];
#pragma unroll
        for (int ft = 0; ft < 8; ++ft)
            wf[ft] = *(const bf16x8*)&Ws[(ft * 16 + m) * LDP + k0];
#pragma unroll
        for (int nt = 0; nt < 2; ++nt)
#pragma unroll
            for (int ft = 0; ft < 8; ++ft)
                acc[nt][ft] = __builtin_amdgcn_mfma_f32_16x16x32_bf16(
                    wf[ft], xf[nt], acc[nt][ft], 0, 0, 0);
    }
#pragma unroll
    for (int nt = 0; nt < 2; ++nt) {
        int n = n0 + (w * 2 + nt) * 16 + m;
        if (n >= NN) continue;
#pragma unroll
        for (int ft = 0; ft < 8; ++ft) {
            f32x4 a = acc[nt][ft];
            uint2 pk;
            pk.x = (uint)f2bf(a[0]) | ((uint)f2bf(a[1]) << 16);
            pk.y = (uint)f2bf(a[2]) | ((uint)f2bf(a[3]) << 16);
            *(uint2*)&H[(size_t)n * 256 + fh * 128 + ft * 16 + quad * 4] = pk;
        }
    }
}

// per-block exclusive scan + dinv
__global__ void k_scan1(const int* __restrict__ cnt, int* __restrict__ off,
                        int* __restrict__ bsum, float* __restrict__ dinv) {
    __shared__ int s[256];
    int br = blockIdx.x / NB_SCAN;
    int blk = blockIdx.x % NB_SCAN;
    int tid = threadIdx.x;
    int i = blk * 256 + tid;
    int v = (i < NN) ? cnt[br * NN + i] : 0;
    if (i < NN) dinv[br * NN + i] = rsqrtf((float)v + 1.0f);
    s[tid] = v;
    __syncthreads();
    for (int d = 1; d < 256; d <<= 1) {
        int t = (tid >= d) ? s[tid - d] : 0;
        __syncthreads();
        s[tid] += t;
        __syncthreads();
    }
    if (i < NN) off[br * NN + i] = s[tid] - v;
    if (tid == 255) bsum[br * 512 + blk] = s[255];
}

__global__ void k_scan2(int* __restrict__ bsum) {
    __shared__ int s[512];
    int br = blockIdx.x;
    int tid = threadIdx.x;
    int v = (tid < NB_SCAN) ? bsum[br * 512 + tid] : 0;
    s[tid] = v;
    __syncthreads();
    for (int d = 1; d < 512; d <<= 1) {
        int t = (tid >= d) ? s[tid - d] : 0;
        __syncthreads();
        s[tid] += t;
        __syncthreads();
    }
    if (tid < NB_SCAN) bsum[br * 512 + tid] = s[tid] - v;
}

__global__ void k_scan3(int* __restrict__ off, const int* __restrict__ bsum,
                        int* __restrict__ cur) {
    int br = blockIdx.x / NB_SCAN;
    int blk = blockIdx.x % NB_SCAN;
    int i = blk * 256 + threadIdx.x;
    if (i < NN) {
        int o = off[br * NN + i] + bsum[br * 512 + blk];
        off[br * NN + i] = o;
        cur[br * NN + i] = o;
    }
}

// Scatter packed edge record {src, coef} — one 8B store per edge.
__global__ void k_scatter(const int* __restrict__ ei, const int* __restrict__ vei,
                          const float* __restrict__ dinv, int* __restrict__ cur,
                          int2* __restrict__ ent) {
    int t = blockIdx.x * blockDim.x + threadIdx.x;
    if (t >= 2 * NE) return;
    int br = t >= NE;
    int e = t - br * NE;
    const int* S = br ? vei : ei;
    int s = S[e], d = S[NE + e];
    int pos = atomicAdd(&cur[br * NN + d], 1);
    int2 rec;
    rec.x = s;
    rec.y = __float_as_int(dinv[br * NN + s] * dinv[br * NN + d]);
    ent[br * NE + pos] = rec;
}

// Fused gather + layer-1 epilogue. 2 nodes per wave (32 lanes x uint2 each),
// packed edge records, 4x unroll.
__global__ void k_gather_ep(const ushort* __restrict__ H, const float* __restrict__ dinv,
                            const int* __restrict__ off, const int* __restrict__ cur,
                            const int2* __restrict__ ent,
                            const float* __restrict__ b1, const float* __restrict__ bv1,
                            const float* __restrict__ W2, const float* __restrict__ Wv2,
                            float* __restrict__ z) {
    int wid = threadIdx.x >> 6;
    int lane = threadIdx.x & 63;
    int half = lane >> 5;
    int l = lane & 31;
    int task = blockIdx.x * 8 + wid * 2 + half;
    int br = task >= NN;
    int n = task - br * NN;

    const int2* en = ent + br * NE;
    size_t hoff = (size_t)br * 128;

    float dv = dinv[br * NN + n];
    uint2 u = *(const uint2*)(H + (size_t)n * 256 + hoff + l * 4);
    float c = dv * dv;
    float a0 = bf2f(u.x & 0xffffu) * c, a1 = bf2f(u.x >> 16) * c;
    float a2 = bf2f(u.y & 0xffffu) * c, a3 = bf2f(u.y >> 16) * c;

    int p = off[br * NN + n], p1 = cur[br * NN + n];
    for (; p + 3 < p1; p += 4) {
        int2 e0 = en[p], e1 = en[p + 1], e2 = en[p + 2], e3 = en[p + 3];
        uint2 v0 = *(const uint2*)(H + (size_t)e0.x * 256 + hoff + l * 4);
        uint2 v1 = *(const uint2*)(H + (size_t)e1.x * 256 + hoff + l * 4);
        uint2 v2 = *(const uint2*)(H + (size_t)e2.x * 256 + hoff + l * 4);
        uint2 v3 = *(const uint2*)(H + (size_t)e3.x * 256 + hoff + l * 4);
        float c0 = __int_as_float(e0.y), c1 = __int_as_float(e1.y);
        float c2 = __int_as_float(e2.y), c3 = __int_as_float(e3.y);
        a0 += bf2f(v0.x & 0xffffu) * c0; a1 += bf2f(v0.x >> 16) * c0;
        a2 += bf2f(v0.y & 0xffffu) * c0; a3 += bf2f(v0.y >> 16) * c0;
        a0 += bf2f(v1.x & 0xffffu) * c1; a1 += bf2f(v1.x >> 16) * c1;
        a2 += bf2f(v1.y & 0xffffu) * c1; a3 += bf2f(v1.y >> 16) * c1;
        a0 += bf2f(v2.x & 0xffffu) * c2; a1 += bf2f(v2.x >> 16) * c2;
        a2 += bf2f(v2.y & 0xffffu) * c2; a3 += bf2f(v2.y >> 16) * c2;
        a0 += bf2f(v3.x & 0xffffu) * c3; a1 += bf2f(v3.x >> 16) * c3;
        a2 += bf2f(v3.y & 0xffffu) * c3; a3 += bf2f(v3.y >> 16) * c3;
    }
    for (; p < p1; ++p) {
        int2 e0 = en[p];
        float c0 = __int_as_float(e0.y);
        uint2 v0 = *(const uint2*)(H + (size_t)e0.x * 256 + hoff + l * 4);
        a0 += bf2f(v0.x & 0xffffu) * c0; a1 += bf2f(v0.x >> 16) * c0;
        a2 += bf2f(v0.y & 0xffffu) * c0; a3 += bf2f(v0.y >> 16) * c0;
    }

    const float* bb = br ? bv1 : b1;
    const float* ww = br ? Wv2 : W2;
    float4 b4 = *(const float4*)&bb[l * 4];
    float4 w4 = *(const float4*)&ww[l * 4];
    float part = fmaxf(a0 + b4.x, 0.f) * w4.x + fmaxf(a1 + b4.y, 0.f) * w4.y
               + fmaxf(a2 + b4.z, 0.f) * w4.z + fmaxf(a3 + b4.w, 0.f) * w4.w;
#pragma unroll
    for (int o = 16; o > 0; o >>= 1) part += __shfl_down(part, o, 32);
    if (l == 0) z[br * NN + n] = part;
}

// Layer-2 aggregation + LDS-batched y reduction (batch is sorted).
__global__ void k_final2(const float* __restrict__ z, const float* __restrict__ dinv,
                         const int* __restrict__ off, const int* __restrict__ cur,
                         const int2* __restrict__ ent,
                         const float* __restrict__ b2, const float* __restrict__ bv2,
                         const int* __restrict__ batch, float* __restrict__ y) {
    __shared__ float ybuf[256];
    __shared__ int gbase_s;
    int br = blockIdx.x >= NB_SCAN;
    int nb = blockIdx.x - br * NB_SCAN;
    int tid = threadIdx.x;
    ybuf[tid] = 0.f;
    if (tid == 0) gbase_s = batch[nb * 256];
    __syncthreads();
    int gbase = gbase_s;
    int n = nb * 256 + tid;
    if (n < NN) {
        float dv = dinv[br * NN + n];
        float acc = z[br * NN + n] * dv * dv;
        int p1 = cur[br * NN + n];
        for (int p = off[br * NN + n]; p < p1; ++p) {
            int2 e = ent[br * NE + p];
            acc += __int_as_float(e.y) * z[br * NN + e.x];
        }
        acc += br ? bv2[0] : b2[0];
        int gi = batch[n] - gbase;
        if (gi < 256) atomicAdd(&ybuf[gi], acc);
        else atomicAdd(&y[batch[n]], acc);
    }
    __syncthreads();
    float v = ybuf[tid];
    if (v != 0.f) atomicAdd(&y[gbase + tid], v);
}

extern "C" void kernel_launch(void* const* d_in, const int* in_sizes, int n_in,
                              void* d_out, int out_size, void* d_ws, size_t ws_size,
                              hipStream_t stream) {
    const int*   tok   = (const int*)d_in[0];
    const float* pe    = (const float*)d_in[1];
    const int*   ei    = (const int*)d_in[2];
    const int*   vei   = (const int*)d_in[3];
    const int*   batch = (const int*)d_in[4];
    const float* embed = (const float*)d_in[5];
    const float* Wtr   = (const float*)d_in[6];
    const float* bt    = (const float*)d_in[7];
    const float* W1    = (const float*)d_in[8];
    const float* b1    = (const float*)d_in[9];
    const float* W2    = (const float*)d_in[10];
    const float* b2    = (const float*)d_in[11];
    const float* Wv1   = (const float*)d_in[12];
    const float* bv1   = (const float*)d_in[13];
    const float* Wv2   = (const float*)d_in[14];
    const float* bv2   = (const float*)d_in[15];

    float* y = (float*)d_out;       // [NG]
    float* x = y + NG;              // [NN*HD], output 1

    char* w = (char*)d_ws;
    ushort* xb   = (ushort*)w;               w += (size_t)NN * HD * 2;
    ushort* H    = (ushort*)w;               w += (size_t)NN * 256 * 2;
    ushort* Wcat = (ushort*)w;               w += 256 * 128 * 2;
    float*  dinv = (float*)w;                w += 2 * NN * 4;
    float*  z    = (float*)w;                w += 2 * NN * 4;
    int*    cnt  = (int*)w;                  w += 2 * NN * 4;
    int*    off  = (int*)w;                  w += 2 * NN * 4;
    int*    cur  = (int*)w;                  w += 2 * NN * 4;
    int2*   ent  = (int2*)w;                 w += (size_t)2 * NE * 8;
    int*    bsum = (int*)w;                  w += 2 * 512 * 4;

    hipMemsetAsync(y, 0, NG * sizeof(float), stream);
    hipMemsetAsync(cnt, 0, 2 * NN * sizeof(int), stream);

    k_front<<<NBX + NBW + NBD, 256, 0, stream>>>(tok, pe, embed, Wtr, bt, x, xb,
                                                 W1, Wv1, Wcat, ei, vei, cnt);
    k_gemm<<<2 * ((NN + 127) / 128), 256, 0, stream>>>(xb, Wcat, H);
    k_scan1<<<2 * NB_SCAN, 256, 0, stream>>>(cnt, off, bsum, dinv);
    k_scan2<<<2, 512, 0, stream>>>(bsum);
    k_scan3<<<2 * NB_SCAN, 256, 0, stream>>>(off, bsum, cur);
    k_scatter<<<(2 * NE + 255) / 256, 256, 0, stream>>>(ei, vei, dinv, cur, ent);
    k_gather_ep<<<2 * NN / 8, 256, 0, stream>>>(H, dinv, off, cur, ent,
                                                b1, bv1, W2, Wv2, z);
    k_final2<<<2 * NB_SCAN, 256, 0, stream>>>(z, dinv, off, cur, ent,
                                              b2, bv2, batch, y);
}

// Round 7
// 253.544 us; speedup vs baseline: 4.4349x; 1.0599x over previous
//
#include <hip/hip_runtime.h>

#define NN 100000
#define NE 220000
#define HD 128
#define NG 4096
#define NPE 5
#define NB_SCAN ((NN + 255) / 256)   // 391
#define NBX4 ((NN * HD / 4) / 256)   // 12500 (exact)
#define NBW 128                      // prep_w blocks
#define NBD ((2 * NE + 255) / 256)   // 1719

typedef unsigned int uint;
typedef unsigned short ushort;
typedef __attribute__((ext_vector_type(8))) short bf16x8;
typedef __attribute__((ext_vector_type(4))) float f32x4;

__device__ __forceinline__ float bf2f(uint u16) {
    return __uint_as_float(u16 << 16);
}
__device__ __forceinline__ ushort f2bf(float f) {
    uint u = __float_as_uint(f);
    u += 0x7fffu + ((u >> 16) & 1u);   // RNE
    return (ushort)(u >> 16);
}

// Fused front: [0,NBX4) compute x/xb (4 feats/thread); then Wcat; then degree.
__global__ void k_front(const int* __restrict__ tok, const float* __restrict__ pe,
                        const float* __restrict__ embed, const float* __restrict__ Wtr,
                        const float* __restrict__ bt,
                        float* __restrict__ x, ushort* __restrict__ xb,
                        const float* __restrict__ W1, const float* __restrict__ Wv1,
                        ushort* __restrict__ Wcat,
                        const int* __restrict__ ei, const int* __restrict__ vei,
                        int* __restrict__ cnt) {
    int b = blockIdx.x;
    if (b < NBX4) {
        int idx = b * 256 + threadIdx.x;        // one float4 of x
        int n = idx >> 5, q = idx & 31;
        int t = tok[n];
        float4 acc = ((const float4*)(embed + (size_t)t * HD))[q];
        float4 bv = ((const float4*)bt)[q];
        acc.x += bv.x; acc.y += bv.y; acc.z += bv.z; acc.w += bv.w;
        const float* pen = pe + n * NPE;
#pragma unroll
        for (int k = 0; k < NPE; ++k) {
            float p = pen[k];
            float4 wv = ((const float4*)(Wtr + k * HD))[q];
            acc.x += p * wv.x; acc.y += p * wv.y;
            acc.z += p * wv.z; acc.w += p * wv.w;
        }
        ((float4*)x)[idx] = acc;
        uint2 pk;
        pk.x = (uint)f2bf(acc.x) | ((uint)f2bf(acc.y) << 16);
        pk.y = (uint)f2bf(acc.z) | ((uint)f2bf(acc.w) << 16);
        ((uint2*)xb)[idx] = pk;
    } else if (b < NBX4 + NBW) {
        int t = (b - NBX4) * 256 + threadIdx.x;   // 32768
        int f = t >> 7, k = t & 127;
        const float* W = (f < HD) ? W1 : Wv1;
        Wcat[t] = f2bf(W[k * HD + (f & 127)]);
    } else {
        int t = (b - NBX4 - NBW) * 256 + threadIdx.x;
        if (t < 2 * NE) {
            int br = t >= NE;
            int e = t - br * NE;
            const int* S = br ? vei : ei;
            atomicAdd(&cnt[br * NN + S[NE + e]], 1);
        }
    }
}

// H[n][f] (f in [0,256)) = xb[n] @ Wcat[f]. 128-node x 128-feat-half tiles.
// A=W (m=f), B=x (n=node) -> D rows = 4 consecutive f -> 8B packed stores.
#define LDP 136
__global__ __launch_bounds__(256) void k_gemm(const ushort* __restrict__ xb,
                                              const ushort* __restrict__ Wt,
                                              ushort* __restrict__ H) {
    __shared__ ushort Ws[128 * LDP];
    __shared__ ushort As[128 * LDP];
    int bi = blockIdx.x;
    int fh = bi & 1;
    int n0 = (bi >> 1) * 128;
    int tid = threadIdx.x;
    {
        const uint4* src = (const uint4*)(Wt + (size_t)fh * 128 * 128);
        uint4* dst = (uint4*)Ws;
        for (int i = tid; i < 2048; i += 256) dst[(i >> 4) * 17 + (i & 15)] = src[i];
    }
    {
        uint4* dst = (uint4*)As;
        for (int i = tid; i < 2048; i += 256) {
            int n = n0 + (i >> 4);
            uint4 v = {0u, 0u, 0u, 0u};
            if (n < NN) v = ((const uint4*)(xb + (size_t)n * HD))[i & 15];
            dst[(i >> 4) * 17 + (i & 15)] = v;
        }
    }
    __syncthreads();
    int w = tid >> 6, lane = tid & 63;
    int m = lane & 15, quad = lane >> 4;
    f32x4 acc[2][8] = {};
#pragma unroll
    for (int kc = 0; kc < 4; ++kc) {
        int k0 = kc * 32 + quad * 8;
        bf16x8 xf[2], wf[8];
#pragma unroll
        for (int nt = 0; nt < 2; ++nt)
            xf[nt] = *(const bf16x8*)&As[((w * 2 + nt) * 16 + m) * LDP + k0];
#pragma unroll
        for (int ft = 0; ft < 8; ++ft)
            wf[ft] = *(const bf16x8*)&Ws[(ft * 16 + m) * LDP + k0];
#pragma unroll
        for (int nt = 0; nt < 2; ++nt)
#pragma unroll
            for (int ft = 0; ft < 8; ++ft)
                acc[nt][ft] = __builtin_amdgcn_mfma_f32_16x16x32_bf16(
                    wf[ft], xf[nt], acc[nt][ft], 0, 0, 0);
    }
#pragma unroll
    for (int nt = 0; nt < 2; ++nt) {
        int n = n0 + (w * 2 + nt) * 16 + m;
        if (n >= NN) continue;
#pragma unroll
        for (int ft = 0; ft < 8; ++ft) {
            f32x4 a = acc[nt][ft];
            uint2 pk;
            pk.x = (uint)f2bf(a[0]) | ((uint)f2bf(a[1]) << 16);
            pk.y = (uint)f2bf(a[2]) | ((uint)f2bf(a[3]) << 16);
            *(uint2*)&H[(size_t)n * 256 + fh * 128 + ft * 16 + quad * 4] = pk;
        }
    }
}

// per-block exclusive scan + dinv
__global__ void k_scan1(const int* __restrict__ cnt, int* __restrict__ off,
                        int* __restrict__ bsum, float* __restrict__ dinv) {
    __shared__ int s[256];
    int br = blockIdx.x / NB_SCAN;
    int blk = blockIdx.x % NB_SCAN;
    int tid = threadIdx.x;
    int i = blk * 256 + tid;
    int v = (i < NN) ? cnt[br * NN + i] : 0;
    if (i < NN) dinv[br * NN + i] = rsqrtf((float)v + 1.0f);
    s[tid] = v;
    __syncthreads();
    for (int d = 1; d < 256; d <<= 1) {
        int t = (tid >= d) ? s[tid - d] : 0;
        __syncthreads();
        s[tid] += t;
        __syncthreads();
    }
    if (i < NN) off[br * NN + i] = s[tid] - v;
    if (tid == 255) bsum[br * 512 + blk] = s[255];
}

__global__ void k_scan2(int* __restrict__ bsum) {
    __shared__ int s[512];
    int br = blockIdx.x;
    int tid = threadIdx.x;
    int v = (tid < NB_SCAN) ? bsum[br * 512 + tid] : 0;
    s[tid] = v;
    __syncthreads();
    for (int d = 1; d < 512; d <<= 1) {
        int t = (tid >= d) ? s[tid - d] : 0;
        __syncthreads();
        s[tid] += t;
        __syncthreads();
    }
    if (tid < NB_SCAN) bsum[br * 512 + tid] = s[tid] - v;
}

__global__ void k_scan3(int* __restrict__ off, const int* __restrict__ bsum,
                        int* __restrict__ cur) {
    int br = blockIdx.x / NB_SCAN;
    int blk = blockIdx.x % NB_SCAN;
    int i = blk * 256 + threadIdx.x;
    if (i < NN) {
        int o = off[br * NN + i] + bsum[br * 512 + blk];
        off[br * NN + i] = o;
        cur[br * NN + i] = o;
    }
}

// Scatter packed edge record {src, coef} — one 8B store per edge.
__global__ void k_scatter(const int* __restrict__ ei, const int* __restrict__ vei,
                          const float* __restrict__ dinv, int* __restrict__ cur,
                          int2* __restrict__ ent) {
    int t = blockIdx.x * blockDim.x + threadIdx.x;
    if (t >= 2 * NE) return;
    int br = t >= NE;
    int e = t - br * NE;
    const int* S = br ? vei : ei;
    int s = S[e], d = S[NE + e];
    int pos = atomicAdd(&cur[br * NN + d], 1);
    int2 rec;
    rec.x = s;
    rec.y = __float_as_int(dinv[br * NN + s] * dinv[br * NN + d]);
    ent[br * NE + pos] = rec;
}

// Fused gather + layer-1 epilogue. 2 nodes per wave (32 lanes x uint2 each),
// packed edge records, 4x unroll.
__global__ void k_gather_ep(const ushort* __restrict__ H, const float* __restrict__ dinv,
                            const int* __restrict__ off, const int* __restrict__ cur,
                            const int2* __restrict__ ent,
                            const float* __restrict__ b1, const float* __restrict__ bv1,
                            const float* __restrict__ W2, const float* __restrict__ Wv2,
                            float* __restrict__ z) {
    int wid = threadIdx.x >> 6;
    int lane = threadIdx.x & 63;
    int half = lane >> 5;
    int l = lane & 31;
    int task = blockIdx.x * 8 + wid * 2 + half;
    int br = task >= NN;
    int n = task - br * NN;

    const int2* en = ent + br * NE;
    size_t hoff = (size_t)br * 128;

    float dv = dinv[br * NN + n];
    uint2 u = *(const uint2*)(H + (size_t)n * 256 + hoff + l * 4);
    float c = dv * dv;
    float a0 = bf2f(u.x & 0xffffu) * c, a1 = bf2f(u.x >> 16) * c;
    float a2 = bf2f(u.y & 0xffffu) * c, a3 = bf2f(u.y >> 16) * c;

    int p = off[br * NN + n], p1 = cur[br * NN + n];
    for (; p + 3 < p1; p += 4) {
        int2 e0 = en[p], e1 = en[p + 1], e2 = en[p + 2], e3 = en[p + 3];
        uint2 v0 = *(const uint2*)(H + (size_t)e0.x * 256 + hoff + l * 4);
        uint2 v1 = *(const uint2*)(H + (size_t)e1.x * 256 + hoff + l * 4);
        uint2 v2 = *(const uint2*)(H + (size_t)e2.x * 256 + hoff + l * 4);
        uint2 v3 = *(const uint2*)(H + (size_t)e3.x * 256 + hoff + l * 4);
        float c0 = __int_as_float(e0.y), c1 = __int_as_float(e1.y);
        float c2 = __int_as_float(e2.y), c3 = __int_as_float(e3.y);
        a0 += bf2f(v0.x & 0xffffu) * c0; a1 += bf2f(v0.x >> 16) * c0;
        a2 += bf2f(v0.y & 0xffffu) * c0; a3 += bf2f(v0.y >> 16) * c0;
        a0 += bf2f(v1.x & 0xffffu) * c1; a1 += bf2f(v1.x >> 16) * c1;
        a2 += bf2f(v1.y & 0xffffu) * c1; a3 += bf2f(v1.y >> 16) * c1;
        a0 += bf2f(v2.x & 0xffffu) * c2; a1 += bf2f(v2.x >> 16) * c2;
        a2 += bf2f(v2.y & 0xffffu) * c2; a3 += bf2f(v2.y >> 16) * c2;
        a0 += bf2f(v3.x & 0xffffu) * c3; a1 += bf2f(v3.x >> 16) * c3;
        a2 += bf2f(v3.y & 0xffffu) * c3; a3 += bf2f(v3.y >> 16) * c3;
    }
    for (; p < p1; ++p) {
        int2 e0 = en[p];
        float c0 = __int_as_float(e0.y);
        uint2 v0 = *(const uint2*)(H + (size_t)e0.x * 256 + hoff + l * 4);
        a0 += bf2f(v0.x & 0xffffu) * c0; a1 += bf2f(v0.x >> 16) * c0;
        a2 += bf2f(v0.y & 0xffffu) * c0; a3 += bf2f(v0.y >> 16) * c0;
    }

    const float* bb = br ? bv1 : b1;
    const float* ww = br ? Wv2 : W2;
    float4 b4 = *(const float4*)&bb[l * 4];
    float4 w4 = *(const float4*)&ww[l * 4];
    float part = fmaxf(a0 + b4.x, 0.f) * w4.x + fmaxf(a1 + b4.y, 0.f) * w4.y
               + fmaxf(a2 + b4.z, 0.f) * w4.z + fmaxf(a3 + b4.w, 0.f) * w4.w;
#pragma unroll
    for (int o = 16; o > 0; o >>= 1) part += __shfl_down(part, o, 32);
    if (l == 0) z[br * NN + n] = part;
}

// Layer-2 aggregation + LDS-batched y reduction (batch is sorted).
__global__ void k_final2(const float* __restrict__ z, const float* __restrict__ dinv,
                         const int* __restrict__ off, const int* __restrict__ cur,
                         const int2* __restrict__ ent,
                         const float* __restrict__ b2, const float* __restrict__ bv2,
                         const int* __restrict__ batch, float* __restrict__ y) {
    __shared__ float ybuf[256];
    __shared__ int gbase_s;
    int br = blockIdx.x >= NB_SCAN;
    int nb = blockIdx.x - br * NB_SCAN;
    int tid = threadIdx.x;
    ybuf[tid] = 0.f;
    if (tid == 0) gbase_s = batch[nb * 256];
    __syncthreads();
    int gbase = gbase_s;
    int n = nb * 256 + tid;
    if (n < NN) {
        float dv = dinv[br * NN + n];
        float acc = z[br * NN + n] * dv * dv;
        int p1 = cur[br * NN + n];
        for (int p = off[br * NN + n]; p < p1; ++p) {
            int2 e = ent[br * NE + p];
            acc += __int_as_float(e.y) * z[br * NN + e.x];
        }
        acc += br ? bv2[0] : b2[0];
        int gi = batch[n] - gbase;
        if (gi < 256) atomicAdd(&ybuf[gi], acc);
        else atomicAdd(&y[batch[n]], acc);
    }
    __syncthreads();
    float v = ybuf[tid];
    if (v != 0.f) atomicAdd(&y[gbase + tid], v);
}

extern "C" void kernel_launch(void* const* d_in, const int* in_sizes, int n_in,
                              void* d_out, int out_size, void* d_ws, size_t ws_size,
                              hipStream_t stream) {
    const int*   tok   = (const int*)d_in[0];
    const float* pe    = (const float*)d_in[1];
    const int*   ei    = (const int*)d_in[2];
    const int*   vei   = (const int*)d_in[3];
    const int*   batch = (const int*)d_in[4];
    const float* embed = (const float*)d_in[5];
    const float* Wtr   = (const float*)d_in[6];
    const float* bt    = (const float*)d_in[7];
    const float* W1    = (const float*)d_in[8];
    const float* b1    = (const float*)d_in[9];
    const float* W2    = (const float*)d_in[10];
    const float* b2    = (const float*)d_in[11];
    const float* Wv1   = (const float*)d_in[12];
    const float* bv1   = (const float*)d_in[13];
    const float* Wv2   = (const float*)d_in[14];
    const float* bv2   = (const float*)d_in[15];

    float* y = (float*)d_out;       // [NG]
    float* x = y + NG;              // [NN*HD], output 1

    char* w = (char*)d_ws;
    ushort* xb   = (ushort*)w;               w += (size_t)NN * HD * 2;
    ushort* H    = (ushort*)w;               w += (size_t)NN * 256 * 2;
    ushort* Wcat = (ushort*)w;               w += 256 * 128 * 2;
    float*  dinv = (float*)w;                w += 2 * NN * 4;
    float*  z    = (float*)w;                w += 2 * NN * 4;
    int*    cnt  = (int*)w;                  w += 2 * NN * 4;
    int*    off  = (int*)w;                  w += 2 * NN * 4;
    int*    cur  = (int*)w;                  w += 2 * NN * 4;
    int2*   ent  = (int2*)w;                 w += (size_t)2 * NE * 8;
    int*    bsum = (int*)w;                  w += 2 * 512 * 4;

    hipMemsetAsync(y, 0, NG * sizeof(float), stream);
    hipMemsetAsync(cnt, 0, 2 * NN * sizeof(int), stream);

    k_front<<<NBX4 + NBW + NBD, 256, 0, stream>>>(tok, pe, embed, Wtr, bt, x, xb,
                                                  W1, Wv1, Wcat, ei, vei, cnt);
    k_gemm<<<2 * ((NN + 127) / 128), 256, 0, stream>>>(xb, Wcat, H);
    k_scan1<<<2 * NB_SCAN, 256, 0, stream>>>(cnt, off, bsum, dinv);
    k_scan2<<<2, 512, 0, stream>>>(bsum);
    k_scan3<<<2 * NB_SCAN, 256, 0, stream>>>(off, bsum, cur);
    k_scatter<<<(2 * NE + 255) / 256, 256, 0, stream>>>(ei, vei, dinv, cur, ent);
    k_gather_ep<<<2 * NN / 8, 256, 0, stream>>>(H, dinv, off, cur, ent,
                                                b1, bv1, W2, Wv2, z);
    k_final2<<<2 * NB_SCAN, 256, 0, stream>>>(z, dinv, off, cur, ent,
                                              b2, bv2, batch, y);
}

// Round 8
// 242.018 us; speedup vs baseline: 4.6461x; 1.0476x over previous
//
#include <hip/hip_runtime.h>

#define NN 100000
#define NE 220000
#define HD 128
#define NG 4096
#define NPE 5
#define NB_SCAN ((NN + 255) / 256)   // 391
#define NBX4 ((NN * HD / 4) / 256)   // 12500 (exact)
#define NBW 128                      // prep_w blocks
#define NBD ((2 * NE + 255) / 256)   // 1719

typedef unsigned int uint;
typedef unsigned short ushort;
typedef __attribute__((ext_vector_type(8))) short bf16x8;
typedef __attribute__((ext_vector_type(4))) float f32x4;

__device__ __forceinline__ float bf2f(uint u16) {
    return __uint_as_float(u16 << 16);
}
__device__ __forceinline__ ushort f2bf(float f) {
    uint u = __float_as_uint(f);
    u += 0x7fffu + ((u >> 16) & 1u);   // RNE
    return (ushort)(u >> 16);
}

// Fused front: [0,NBX4) compute x/xb (4 feats/thread); then Wcat; then degree.
__global__ void k_front(const int* __restrict__ tok, const float* __restrict__ pe,
                        const float* __restrict__ embed, const float* __restrict__ Wtr,
                        const float* __restrict__ bt,
                        float* __restrict__ x, ushort* __restrict__ xb,
                        const float* __restrict__ W1, const float* __restrict__ Wv1,
                        ushort* __restrict__ Wcat,
                        const int* __restrict__ ei, const int* __restrict__ vei,
                        int* __restrict__ cnt) {
    int b = blockIdx.x;
    if (b < NBX4) {
        int idx = b * 256 + threadIdx.x;        // one float4 of x
        int n = idx >> 5, q = idx & 31;
        int t = tok[n];
        float4 acc = ((const float4*)(embed + (size_t)t * HD))[q];
        float4 bv = ((const float4*)bt)[q];
        acc.x += bv.x; acc.y += bv.y; acc.z += bv.z; acc.w += bv.w;
        const float* pen = pe + n * NPE;
#pragma unroll
        for (int k = 0; k < NPE; ++k) {
            float p = pen[k];
            float4 wv = ((const float4*)(Wtr + k * HD))[q];
            acc.x += p * wv.x; acc.y += p * wv.y;
            acc.z += p * wv.z; acc.w += p * wv.w;
        }
        ((float4*)x)[idx] = acc;
        uint2 pk;
        pk.x = (uint)f2bf(acc.x) | ((uint)f2bf(acc.y) << 16);
        pk.y = (uint)f2bf(acc.z) | ((uint)f2bf(acc.w) << 16);
        ((uint2*)xb)[idx] = pk;
    } else if (b < NBX4 + NBW) {
        int t = (b - NBX4) * 256 + threadIdx.x;   // 32768
        int f = t >> 7, k = t & 127;
        const float* W = (f < HD) ? W1 : Wv1;
        Wcat[t] = f2bf(W[k * HD + (f & 127)]);
    } else {
        int t = (b - NBX4 - NBW) * 256 + threadIdx.x;
        if (t < 2 * NE) {
            int br = t >= NE;
            int e = t - br * NE;
            const int* S = br ? vei : ei;
            atomicAdd(&cnt[br * NN + S[NE + e]], 1);
        }
    }
}

// H[n][f] (f in [0,256)) = xb[n] @ Wcat[f]. 128-node x 128-feat-half tiles.
#define LDP 136
__global__ __launch_bounds__(256) void k_gemm(const ushort* __restrict__ xb,
                                              const ushort* __restrict__ Wt,
                                              ushort* __restrict__ H) {
    __shared__ ushort Ws[128 * LDP];
    __shared__ ushort As[128 * LDP];
    int bi = blockIdx.x;
    int fh = bi & 1;
    int n0 = (bi >> 1) * 128;
    int tid = threadIdx.x;
    {
        const uint4* src = (const uint4*)(Wt + (size_t)fh * 128 * 128);
        uint4* dst = (uint4*)Ws;
        for (int i = tid; i < 2048; i += 256) dst[(i >> 4) * 17 + (i & 15)] = src[i];
    }
    {
        uint4* dst = (uint4*)As;
        for (int i = tid; i < 2048; i += 256) {
            int n = n0 + (i >> 4);
            uint4 v = {0u, 0u, 0u, 0u};
            if (n < NN) v = ((const uint4*)(xb + (size_t)n * HD))[i & 15];
            dst[(i >> 4) * 17 + (i & 15)] = v;
        }
    }
    __syncthreads();
    int w = tid >> 6, lane = tid & 63;
    int m = lane & 15, quad = lane >> 4;
    f32x4 acc[2][8] = {};
#pragma unroll
    for (int kc = 0; kc < 4; ++kc) {
        int k0 = kc * 32 + quad * 8;
        bf16x8 xf[2], wf[8];
#pragma unroll
        for (int nt = 0; nt < 2; ++nt)
            xf[nt] = *(const bf16x8*)&As[((w * 2 + nt) * 16 + m) * LDP + k0];
#pragma unroll
        for (int ft = 0; ft < 8; ++ft)
            wf[ft] = *(const bf16x8*)&Ws[(ft * 16 + m) * LDP + k0];
#pragma unroll
        for (int nt = 0; nt < 2; ++nt)
#pragma unroll
            for (int ft = 0; ft < 8; ++ft)
                acc[nt][ft] = __builtin_amdgcn_mfma_f32_16x16x32_bf16(
                    wf[ft], xf[nt], acc[nt][ft], 0, 0, 0);
    }
#pragma unroll
    for (int nt = 0; nt < 2; ++nt) {
        int n = n0 + (w * 2 + nt) * 16 + m;
        if (n >= NN) continue;
#pragma unroll
        for (int ft = 0; ft < 8; ++ft) {
            f32x4 a = acc[nt][ft];
            uint2 pk;
            pk.x = (uint)f2bf(a[0]) | ((uint)f2bf(a[1]) << 16);
            pk.y = (uint)f2bf(a[2]) | ((uint)f2bf(a[3]) << 16);
            *(uint2*)&H[(size_t)n * 256 + fh * 128 + ft * 16 + quad * 4] = pk;
        }
    }
}

// per-block exclusive scan + dinv
__global__ void k_scan1(const int* __restrict__ cnt, int* __restrict__ off,
                        int* __restrict__ bsum, float* __restrict__ dinv) {
    __shared__ int s[256];
    int br = blockIdx.x / NB_SCAN;
    int blk = blockIdx.x % NB_SCAN;
    int tid = threadIdx.x;
    int i = blk * 256 + tid;
    int v = (i < NN) ? cnt[br * NN + i] : 0;
    if (i < NN) dinv[br * NN + i] = rsqrtf((float)v + 1.0f);
    s[tid] = v;
    __syncthreads();
    for (int d = 1; d < 256; d <<= 1) {
        int t = (tid >= d) ? s[tid - d] : 0;
        __syncthreads();
        s[tid] += t;
        __syncthreads();
    }
    if (i < NN) off[br * NN + i] = s[tid] - v;
    if (tid == 255) bsum[br * 512 + blk] = s[255];
}

__global__ void k_scan2(int* __restrict__ bsum) {
    __shared__ int s[512];
    int br = blockIdx.x;
    int tid = threadIdx.x;
    int v = (tid < NB_SCAN) ? bsum[br * 512 + tid] : 0;
    s[tid] = v;
    __syncthreads();
    for (int d = 1; d < 512; d <<= 1) {
        int t = (tid >= d) ? s[tid - d] : 0;
        __syncthreads();
        s[tid] += t;
        __syncthreads();
    }
    if (tid < NB_SCAN) bsum[br * 512 + tid] = s[tid] - v;
}

__global__ void k_scan3(int* __restrict__ off, const int* __restrict__ bsum,
                        int* __restrict__ cur) {
    int br = blockIdx.x / NB_SCAN;
    int blk = blockIdx.x % NB_SCAN;
    int i = blk * 256 + threadIdx.x;
    if (i < NN) {
        int o = off[br * NN + i] + bsum[br * 512 + blk];
        off[br * NN + i] = o;
        cur[br * NN + i] = o;
    }
}

// Scatter packed edge record {src, coef} — one 8B store per edge.
__global__ void k_scatter(const int* __restrict__ ei, const int* __restrict__ vei,
                          const float* __restrict__ dinv, int* __restrict__ cur,
                          int2* __restrict__ ent) {
    int t = blockIdx.x * blockDim.x + threadIdx.x;
    if (t >= 2 * NE) return;
    int br = t >= NE;
    int e = t - br * NE;
    const int* S = br ? vei : ei;
    int s = S[e], d = S[NE + e];
    int pos = atomicAdd(&cur[br * NN + d], 1);
    int2 rec;
    rec.x = s;
    rec.y = __float_as_int(dinv[br * NN + s] * dinv[br * NN + d]);
    ent[br * NE + pos] = rec;
}

// Fused gather + layer-1 epilogue. 2 nodes per wave (32 lanes x uint2 each).
// Clamped 4-wide edge batches: all record loads + H loads independent, so
// even deg<=4 nodes (the vast majority) get full MLP. ent has +8 rec padding.
__global__ void k_gather_ep(const ushort* __restrict__ H, const float* __restrict__ dinv,
                            const int* __restrict__ off, const int* __restrict__ cur,
                            const int2* __restrict__ ent,
                            const float* __restrict__ b1, const float* __restrict__ bv1,
                            const float* __restrict__ W2, const float* __restrict__ Wv2,
                            float* __restrict__ z) {
    int wid = threadIdx.x >> 6;
    int lane = threadIdx.x & 63;
    int half = lane >> 5;
    int l = lane & 31;
    int task = blockIdx.x * 8 + wid * 2 + half;
    int br = task >= NN;
    int n = task - br * NN;

    const int2* en = ent + br * NE;
    size_t hoff = (size_t)br * 128;

    float dv = dinv[br * NN + n];
    uint2 u = *(const uint2*)(H + (size_t)n * 256 + hoff + l * 4);
    float c = dv * dv;
    float a0 = bf2f(u.x & 0xffffu) * c, a1 = bf2f(u.x >> 16) * c;
    float a2 = bf2f(u.y & 0xffffu) * c, a3 = bf2f(u.y >> 16) * c;

    int p0 = off[br * NN + n], p1 = cur[br * NN + n];
    for (int p = p0; p < p1; p += 4) {
        int2 e0 = en[p], e1 = en[p + 1], e2 = en[p + 2], e3 = en[p + 3];
        int s0 = e0.x;
        int s1 = (p + 1 < p1) ? e1.x : n;
        int s2 = (p + 2 < p1) ? e2.x : n;
        int s3 = (p + 3 < p1) ? e3.x : n;
        float c0 = __int_as_float(e0.y);
        float c1 = (p + 1 < p1) ? __int_as_float(e1.y) : 0.f;
        float c2 = (p + 2 < p1) ? __int_as_float(e2.y) : 0.f;
        float c3 = (p + 3 < p1) ? __int_as_float(e3.y) : 0.f;
        uint2 v0 = *(const uint2*)(H + (size_t)s0 * 256 + hoff + l * 4);
        uint2 v1 = *(const uint2*)(H + (size_t)s1 * 256 + hoff + l * 4);
        uint2 v2 = *(const uint2*)(H + (size_t)s2 * 256 + hoff + l * 4);
        uint2 v3 = *(const uint2*)(H + (size_t)s3 * 256 + hoff + l * 4);
        a0 += bf2f(v0.x & 0xffffu) * c0; a1 += bf2f(v0.x >> 16) * c0;
        a2 += bf2f(v0.y & 0xffffu) * c0; a3 += bf2f(v0.y >> 16) * c0;
        a0 += bf2f(v1.x & 0xffffu) * c1; a1 += bf2f(v1.x >> 16) * c1;
        a2 += bf2f(v1.y & 0xffffu) * c1; a3 += bf2f(v1.y >> 16) * c1;
        a0 += bf2f(v2.x & 0xffffu) * c2; a1 += bf2f(v2.x >> 16) * c2;
        a2 += bf2f(v2.y & 0xffffu) * c2; a3 += bf2f(v2.y >> 16) * c2;
        a0 += bf2f(v3.x & 0xffffu) * c3; a1 += bf2f(v3.x >> 16) * c3;
        a2 += bf2f(v3.y & 0xffffu) * c3; a3 += bf2f(v3.y >> 16) * c3;
    }

    const float* bb = br ? bv1 : b1;
    const float* ww = br ? Wv2 : W2;
    float4 b4 = *(const float4*)&bb[l * 4];
    float4 w4 = *(const float4*)&ww[l * 4];
    float part = fmaxf(a0 + b4.x, 0.f) * w4.x + fmaxf(a1 + b4.y, 0.f) * w4.y
               + fmaxf(a2 + b4.z, 0.f) * w4.z + fmaxf(a3 + b4.w, 0.f) * w4.w;
#pragma unroll
    for (int o = 16; o > 0; o >>= 1) part += __shfl_down(part, o, 32);
    if (l == 0) z[br * NN + n] = part;
}

// Layer-2 aggregation + LDS-batched y reduction (batch is sorted).
// Clamped 4-wide z-walk for MLP.
__global__ void k_final2(const float* __restrict__ z, const float* __restrict__ dinv,
                         const int* __restrict__ off, const int* __restrict__ cur,
                         const int2* __restrict__ ent,
                         const float* __restrict__ b2, const float* __restrict__ bv2,
                         const int* __restrict__ batch, float* __restrict__ y) {
    __shared__ float ybuf[256];
    __shared__ int gbase_s;
    int br = blockIdx.x >= NB_SCAN;
    int nb = blockIdx.x - br * NB_SCAN;
    int tid = threadIdx.x;
    ybuf[tid] = 0.f;
    if (tid == 0) gbase_s = batch[nb * 256];
    __syncthreads();
    int gbase = gbase_s;
    int n = nb * 256 + tid;
    if (n < NN) {
        const int2* en = ent + br * NE;
        float dv = dinv[br * NN + n];
        float acc = z[br * NN + n] * dv * dv;
        int p1 = cur[br * NN + n];
        for (int p = off[br * NN + n]; p < p1; p += 4) {
            int2 e0 = en[p], e1 = en[p + 1], e2 = en[p + 2], e3 = en[p + 3];
            int s0 = e0.x;
            int s1 = (p + 1 < p1) ? e1.x : n;
            int s2 = (p + 2 < p1) ? e2.x : n;
            int s3 = (p + 3 < p1) ? e3.x : n;
            float c0 = __int_as_float(e0.y);
            float c1 = (p + 1 < p1) ? __int_as_float(e1.y) : 0.f;
            float c2 = (p + 2 < p1) ? __int_as_float(e2.y) : 0.f;
            float c3 = (p + 3 < p1) ? __int_as_float(e3.y) : 0.f;
            acc += c0 * z[br * NN + s0] + c1 * z[br * NN + s1]
                 + c2 * z[br * NN + s2] + c3 * z[br * NN + s3];
        }
        acc += br ? bv2[0] : b2[0];
        int gi = batch[n] - gbase;
        if (gi < 256) atomicAdd(&ybuf[gi], acc);
        else atomicAdd(&y[batch[n]], acc);
    }
    __syncthreads();
    float v = ybuf[tid];
    if (v != 0.f) atomicAdd(&y[gbase + tid], v);
}

extern "C" void kernel_launch(void* const* d_in, const int* in_sizes, int n_in,
                              void* d_out, int out_size, void* d_ws, size_t ws_size,
                              hipStream_t stream) {
    const int*   tok   = (const int*)d_in[0];
    const float* pe    = (const float*)d_in[1];
    const int*   ei    = (const int*)d_in[2];
    const int*   vei   = (const int*)d_in[3];
    const int*   batch = (const int*)d_in[4];
    const float* embed = (const float*)d_in[5];
    const float* Wtr   = (const float*)d_in[6];
    const float* bt    = (const float*)d_in[7];
    const float* W1    = (const float*)d_in[8];
    const float* b1    = (const float*)d_in[9];
    const float* W2    = (const float*)d_in[10];
    const float* b2    = (const float*)d_in[11];
    const float* Wv1   = (const float*)d_in[12];
    const float* bv1   = (const float*)d_in[13];
    const float* Wv2   = (const float*)d_in[14];
    const float* bv2   = (const float*)d_in[15];

    float* y = (float*)d_out;       // [NG]
    float* x = y + NG;              // [NN*HD], output 1

    char* w = (char*)d_ws;
    ushort* xb   = (ushort*)w;               w += (size_t)NN * HD * 2;
    ushort* H    = (ushort*)w;               w += (size_t)NN * 256 * 2;
    ushort* Wcat = (ushort*)w;               w += 256 * 128 * 2;
    float*  dinv = (float*)w;                w += 2 * NN * 4;
    float*  z    = (float*)w;                w += 2 * NN * 4;
    int*    cnt  = (int*)w;                  w += 2 * NN * 4;
    int*    off  = (int*)w;                  w += 2 * NN * 4;
    int*    cur  = (int*)w;                  w += 2 * NN * 4;
    int2*   ent  = (int2*)w;                 w += (size_t)(2 * NE + 8) * 8;  // +8 pad
    int*    bsum = (int*)w;                  w += 2 * 512 * 4;

    hipMemsetAsync(y, 0, NG * sizeof(float), stream);
    hipMemsetAsync(cnt, 0, 2 * NN * sizeof(int), stream);

    k_front<<<NBX4 + NBW + NBD, 256, 0, stream>>>(tok, pe, embed, Wtr, bt, x, xb,
                                                  W1, Wv1, Wcat, ei, vei, cnt);
    k_gemm<<<2 * ((NN + 127) / 128), 256, 0, stream>>>(xb, Wcat, H);
    k_scan1<<<2 * NB_SCAN, 256, 0, stream>>>(cnt, off, bsum, dinv);
    k_scan2<<<2, 512, 0, stream>>>(bsum);
    k_scan3<<<2 * NB_SCAN, 256, 0, stream>>>(off, bsum, cur);
    k_scatter<<<(2 * NE + 255) / 256, 256, 0, stream>>>(ei, vei, dinv, cur, ent);
    k_gather_ep<<<2 * NN / 8, 256, 0, stream>>>(H, dinv, off, cur, ent,
                                                b1, bv1, W2, Wv2, z);
    k_final2<<<2 * NB_SCAN, 256, 0, stream>>>(z, dinv, off, cur, ent,
                                              b2, bv2, batch, y);
}